// Round 2
// baseline (1161.306 us; speedup 1.0000x reference)
//
#include <hip/hip_runtime.h>
#include <hip/hip_bf16.h>

typedef __hip_bfloat16 bf16;

__device__ __forceinline__ float b2f(bf16 v) { return __bfloat162float(v); }
__device__ __forceinline__ float u2f(unsigned short u) {
    return __uint_as_float(((unsigned)u) << 16);
}
__device__ __forceinline__ float leaky(float v) { return v > 0.f ? v : 0.2f * v; }

// flag-aware weight read by ELEMENT index: flag==1 -> f32 storage, else bf16
__device__ __forceinline__ float ldw(const void* p, size_t i, int f32) {
    return f32 ? ((const float*)p)[i] : b2f(((const bf16*)p)[i]);
}

// ---------------- dtype detection ----------------
__global__ void k_detect(const void* x, int* flag) {
    int i = blockIdx.x * blockDim.x + threadIdx.x;
    float v = b2f(((const bf16*)x)[i]);
    if (!(fabsf(v) < 1e10f)) atomicOr(flag, 1);  // NaN/inf/huge -> f32 storage
}

__global__ void k_convert(const void* __restrict__ x, float* __restrict__ A, int n,
                          const int* __restrict__ flag) {
    int i = blockIdx.x * blockDim.x + threadIdx.x;
    int f32 = *flag;
    if (i < n) A[i] = f32 ? ((const float*)x)[i] : b2f(((const bf16*)x)[i]);
}

__global__ void k_zero(int* __restrict__ p, int n) {
    int i = blockIdx.x * blockDim.x + threadIdx.x;
    if (i < n) p[i] = 0;
}

__global__ void k_hist(const int* __restrict__ ei, int* __restrict__ counts, int E) {
    int e = blockIdx.x * blockDim.x + threadIdx.x;
    if (e < E) atomicAdd(&counts[ei[E + e]], 1);
}

__global__ void k_scan1(const int* __restrict__ counts, int* __restrict__ offs,
                        int* __restrict__ bsums, int n) {
    __shared__ int s[256];
    int tid = threadIdx.x;
    int i = blockIdx.x * 256 + tid;
    int v = (i < n) ? counts[i] : 0;
    s[tid] = v;
    __syncthreads();
    for (int d = 1; d < 256; d <<= 1) {
        int t = (tid >= d) ? s[tid - d] : 0;
        __syncthreads();
        s[tid] += t;
        __syncthreads();
    }
    int incl = s[tid];
    if (i < n) offs[i] = incl - v;
    if (tid == 255) bsums[blockIdx.x] = incl;
}

__global__ void k_scan2(int* __restrict__ bsums, int nb) {
    __shared__ int s[512];
    int tid = threadIdx.x;
    int v = (tid < nb) ? bsums[tid] : 0;
    s[tid] = v;
    __syncthreads();
    for (int d = 1; d < 512; d <<= 1) {
        int t = (tid >= d) ? s[tid - d] : 0;
        __syncthreads();
        s[tid] += t;
        __syncthreads();
    }
    bsums[tid] = s[tid] - v;
}

__global__ void k_scan3(int* __restrict__ offs, int* __restrict__ cursor,
                        const int* __restrict__ bsums, int n) {
    int i = blockIdx.x * 256 + threadIdx.x;
    if (i < n) {
        int o = offs[i] + bsums[blockIdx.x];
        offs[i] = o;
        cursor[i] = o;
    }
}

__global__ void k_scatter(const int* __restrict__ ei, int* __restrict__ cursor,
                          int* __restrict__ adj, int E) {
    int e = blockIdx.x * blockDim.x + threadIdx.x;
    if (e < E) {
        int d = ei[E + e];
        int pos = atomicAdd(&cursor[d], 1);
        adj[pos] = ei[e];
    }
}

__global__ void k_node0(const int* __restrict__ batch, int* __restrict__ node0, int n) {
    int i = blockIdx.x * blockDim.x + threadIdx.x;
    if (i < n) {
        int b = batch[i];
        if (i == 0 || batch[i - 1] != b) node0[b] = i;
    }
}

// ---------------- GEMM: B[N,128] = A[N,128] @ W[128,128] ----------------
__global__ __launch_bounds__(256) void k_gemm_bf16(const float* __restrict__ A,
                                                   const void* __restrict__ Wv,
                                                   size_t woff,
                                                   float* __restrict__ B, int N,
                                                   const int* __restrict__ flag) {
    if (*flag != 0) return;
    const bf16* Wb = (const bf16*)Wv + woff;
    __shared__ unsigned short Ws[128 * 128];
    __shared__ float As[32 * 132];

    int t = threadIdx.x;
    int r0 = blockIdx.x * 32;

    const ushort4* Wg = (const ushort4*)Wb;
    for (int i = t; i < 4096; i += 256) ((ushort4*)Ws)[i] = Wg[i];

    const float4* Ag = (const float4*)(A + (size_t)r0 * 128);
    for (int i = t; i < 1024; i += 256) {
        float4 v = Ag[i];
        int row = (i * 4) >> 7;
        int col = (i * 4) & 127;
        *(float4*)&As[row * 132 + col] = v;
    }
    __syncthreads();

    int tx = t & 31;
    int ty = t >> 5;
    float acc[4][4];
#pragma unroll
    for (int i = 0; i < 4; i++)
#pragma unroll
        for (int j = 0; j < 4; j++) acc[i][j] = 0.f;

#pragma unroll 8
    for (int k = 0; k < 128; k++) {
        float a0 = As[(ty * 4 + 0) * 132 + k];
        float a1 = As[(ty * 4 + 1) * 132 + k];
        float a2 = As[(ty * 4 + 2) * 132 + k];
        float a3 = As[(ty * 4 + 3) * 132 + k];
        ushort4 w4 = *(const ushort4*)&Ws[k * 128 + tx * 4];
        float w0 = u2f(w4.x), w1 = u2f(w4.y), w2 = u2f(w4.z), w3 = u2f(w4.w);
        acc[0][0] += a0 * w0; acc[0][1] += a0 * w1; acc[0][2] += a0 * w2; acc[0][3] += a0 * w3;
        acc[1][0] += a1 * w0; acc[1][1] += a1 * w1; acc[1][2] += a1 * w2; acc[1][3] += a1 * w3;
        acc[2][0] += a2 * w0; acc[2][1] += a2 * w1; acc[2][2] += a2 * w2; acc[2][3] += a2 * w3;
        acc[3][0] += a3 * w0; acc[3][1] += a3 * w1; acc[3][2] += a3 * w2; acc[3][3] += a3 * w3;
    }

#pragma unroll
    for (int i = 0; i < 4; i++) {
        int row = r0 + ty * 4 + i;
        if (row < N) {
            float4 v = make_float4(acc[i][0], acc[i][1], acc[i][2], acc[i][3]);
            *(float4*)&B[(size_t)row * 128 + tx * 4] = v;
        }
    }
}

__global__ __launch_bounds__(256) void k_gemm_f32(const float* __restrict__ A,
                                                  const void* __restrict__ Wv,
                                                  size_t woff,
                                                  float* __restrict__ B, int N,
                                                  const int* __restrict__ flag) {
    if (*flag != 1) return;
    const float* W = (const float*)Wv + woff;
    __shared__ float Ws[64 * 128];
    __shared__ float As[32 * 132];

    int t = threadIdx.x;
    int r0 = blockIdx.x * 32;

    const float4* Ag = (const float4*)(A + (size_t)r0 * 128);
    for (int i = t; i < 1024; i += 256) {
        float4 v = Ag[i];
        int row = (i * 4) >> 7;
        int col = (i * 4) & 127;
        *(float4*)&As[row * 132 + col] = v;
    }

    int tx = t & 31;
    int ty = t >> 5;
    float acc[4][4];
#pragma unroll
    for (int i = 0; i < 4; i++)
#pragma unroll
        for (int j = 0; j < 4; j++) acc[i][j] = 0.f;

    for (int half = 0; half < 2; half++) {
        __syncthreads();
        const float4* Wg = (const float4*)(W + half * 64 * 128);
        for (int i = t; i < 2048; i += 256) ((float4*)Ws)[i] = Wg[i];
        __syncthreads();
#pragma unroll 8
        for (int k = 0; k < 64; k++) {
            int kk = half * 64 + k;
            float a0 = As[(ty * 4 + 0) * 132 + kk];
            float a1 = As[(ty * 4 + 1) * 132 + kk];
            float a2 = As[(ty * 4 + 2) * 132 + kk];
            float a3 = As[(ty * 4 + 3) * 132 + kk];
            float4 wv = *(const float4*)&Ws[k * 128 + tx * 4];
            acc[0][0] += a0 * wv.x; acc[0][1] += a0 * wv.y; acc[0][2] += a0 * wv.z; acc[0][3] += a0 * wv.w;
            acc[1][0] += a1 * wv.x; acc[1][1] += a1 * wv.y; acc[1][2] += a1 * wv.z; acc[1][3] += a1 * wv.w;
            acc[2][0] += a2 * wv.x; acc[2][1] += a2 * wv.y; acc[2][2] += a2 * wv.z; acc[2][3] += a2 * wv.w;
            acc[3][0] += a3 * wv.x; acc[3][1] += a3 * wv.y; acc[3][2] += a3 * wv.z; acc[3][3] += a3 * wv.w;
        }
    }

#pragma unroll
    for (int i = 0; i < 4; i++) {
        int row = r0 + ty * 4 + i;
        if (row < N) {
            float4 v = make_float4(acc[i][0], acc[i][1], acc[i][2], acc[i][3]);
            *(float4*)&B[(size_t)row * 128 + tx * 4] = v;
        }
    }
}

// ---------------- attention scalars ----------------
__global__ void k_asad(const float* __restrict__ B, const void* __restrict__ asrc,
                       const void* __restrict__ adst, size_t woff,
                       float4* __restrict__ asad, int n, const int* __restrict__ flag) {
    int node = (blockIdx.x * blockDim.x + threadIdx.x) >> 6;
    int lane = threadIdx.x & 63;
    if (node >= n) return;
    int f32 = *flag;
    float h0 = B[(size_t)node * 128 + lane];
    float h1 = B[(size_t)node * 128 + 64 + lane];
    float as0 = h0 * ldw(asrc, woff + lane, f32);
    float as1 = h1 * ldw(asrc, woff + 64 + lane, f32);
    float ad0 = h0 * ldw(adst, woff + lane, f32);
    float ad1 = h1 * ldw(adst, woff + 64 + lane, f32);
#pragma unroll
    for (int off = 32; off > 0; off >>= 1) {
        as0 += __shfl_down(as0, off);
        as1 += __shfl_down(as1, off);
        ad0 += __shfl_down(ad0, off);
        ad1 += __shfl_down(ad1, off);
    }
    if (lane == 0) asad[node] = make_float4(as0, as1, ad0, ad1);
}

// ---------------- GAT aggregation ----------------
__global__ void k_agg(const float* __restrict__ B, const float4* __restrict__ asad,
                      const int* __restrict__ offs, const int* __restrict__ counts,
                      const int* __restrict__ adj, const void* __restrict__ bias,
                      size_t woff, float* __restrict__ A, int n, int dorelu,
                      const int* __restrict__ flag) {
    int node = (blockIdx.x * blockDim.x + threadIdx.x) >> 6;
    int lane = threadIdx.x & 63;
    if (node >= n) return;
    int f32 = *flag;

    float4 an = asad[node];
    float ad0 = an.z, ad1 = an.w;

    float m0 = leaky(an.x + ad0);
    float m1 = leaky(an.y + ad1);
    float s0 = 1.f, s1 = 1.f;
    float acc0 = B[(size_t)node * 128 + lane];
    float acc1 = B[(size_t)node * 128 + 64 + lane];

    int o = offs[node];
    int c = counts[node];
    for (int i = 0; i < c; i++) {
        int src = adj[o + i];
        float4 av = asad[src];
        float e0 = leaky(av.x + ad0);
        float e1 = leaky(av.y + ad1);
        float h0 = B[(size_t)src * 128 + lane];
        float h1 = B[(size_t)src * 128 + 64 + lane];
        float mn0 = fmaxf(m0, e0);
        float corr0 = __expf(m0 - mn0);
        float p0 = __expf(e0 - mn0);
        s0 = s0 * corr0 + p0;
        acc0 = acc0 * corr0 + p0 * h0;
        m0 = mn0;
        float mn1 = fmaxf(m1, e1);
        float corr1 = __expf(m1 - mn1);
        float p1 = __expf(e1 - mn1);
        s1 = s1 * corr1 + p1;
        acc1 = acc1 * corr1 + p1 * h1;
        m1 = mn1;
    }

    float o0 = acc0 / (s0 + 1e-16f) + ldw(bias, woff + lane, f32);
    float o1 = acc1 / (s1 + 1e-16f) + ldw(bias, woff + 64 + lane, f32);
    if (dorelu) { o0 = fmaxf(o0, 0.f); o1 = fmaxf(o1, 0.f); }
    A[(size_t)node * 128 + lane] = o0;
    A[(size_t)node * 128 + 64 + lane] = o1;
}

// ---------------- heads ----------------
__global__ __launch_bounds__(64) void k_heads(
    const float* __restrict__ A, const void* __restrict__ x, const int* __restrict__ node0,
    const void* sW, const void* sb,
    const void* pW1, const void* pb1, const void* pW2, const void* pb2,
    const void* cW1, const void* cb1, const void* cW2, const void* cb2,
    const void* fW1, const void* fb1, const void* fW2, const void* fb2,
    const void* bW1, const void* bb1, const void* bW2, const void* bb2,
    const void* zW1, const void* zb1, const void* zW2, const void* zb2,
    void* __restrict__ outv, const int* __restrict__ flag) {
    int g = blockIdx.x;
    int t = threadIdx.x;
    int f32 = *flag;
    bf16* outb = (bf16*)outv;
    float* outf = (float*)outv;
    __shared__ float in150[152];
    __shared__ float zf[64];
    __shared__ float tmp[64];
    __shared__ float bin[96];

#define STORE_OUT(idx, val) do { if (f32) outf[idx] = (val); else outb[idx] = __float2bfloat16(val); } while (0)

    int n0 = node0[g];
    in150[t] = A[(size_t)n0 * 128 + t];
    in150[64 + t] = A[(size_t)n0 * 128 + 64 + t];
    if (t < 22) in150[128 + t] = ldw(x, (size_t)n0 * 128 + t, f32);
    __syncthreads();

    {
        float a = ldw(sb, t, f32);
        for (int i = 0; i < 150; i++) a += in150[i] * ldw(sW, i * 64 + t, f32);
        a = fmaxf(a, 0.f);
        zf[t] = a;
        bin[t] = a;
        if (t < 22) bin[64 + t] = in150[128 + t];
    }
    __syncthreads();

    for (int k = 0; k < 3; k++) {
        float a = ldw(pb1, k * 64 + t, f32);
        for (int i = 0; i < 64; i++) a += zf[i] * ldw(pW1, k * 4096 + i * 64 + t, f32);
        a = fmaxf(a, 0.f);
        tmp[t] = a;
        __syncthreads();
        if (t < 3) {
            float o = ldw(pb2, k * 3 + t, f32);
            for (int j = 0; j < 64; j++) o += tmp[j] * ldw(pW2, k * 192 + j * 3 + t, f32);
            STORE_OUT(k * 768 + g * 3 + t, o);
        }
        __syncthreads();
    }

    {
        float a = ldw(cb1, t, f32);
        for (int i = 0; i < 64; i++) a += zf[i] * ldw(cW1, i * 64 + t, f32);
        a = fmaxf(a, 0.f);
        tmp[t] = a;
        __syncthreads();
        if (t < 5) {
            float o = ldw(cb2, t, f32);
            for (int j = 0; j < 64; j++) o += tmp[j] * ldw(cW2, j * 5 + t, f32);
            bin[86 + t] = o;
            STORE_OUT(2304 + g * 5 + t, o);
        }
        __syncthreads();
    }

    for (int k = 0; k < 2; k++) {
        float a = ldw(fb1, k * 64 + t, f32);
        for (int i = 0; i < 64; i++) a += zf[i] * ldw(fW1, k * 4096 + i * 64 + t, f32);
        a = fmaxf(a, 0.f);
        tmp[t] = a;
        __syncthreads();
        if (t == 0) {
            float o = ldw(fb2, k, f32);
            for (int j = 0; j < 64; j++) o += tmp[j] * ldw(fW2, k * 64 + j, f32);
            bin[91 + k] = o;
            STORE_OUT(3584 + k * 256 + g, o);
        }
        __syncthreads();
    }

    {
        float a = ldw(bb1, t, f32);
        for (int i = 0; i < 93; i++) a += bin[i] * ldw(bW1, i * 64 + t, f32);
        a = fmaxf(a, 0.f);
        tmp[t] = a;
        __syncthreads();
        if (t == 0) {
            float o = ldw(bb2, 0, f32);
            for (int j = 0; j < 64; j++) o += tmp[j] * ldw(bW2, j, f32);
            bin[93] = o;
            STORE_OUT(4096 + g, o);
        }
        __syncthreads();
    }

    {
        float a = ldw(zb1, t, f32);
        for (int i = 0; i < 94; i++) a += bin[i] * ldw(zW1, i * 64 + t, f32);
        a = fmaxf(a, 0.f);
        tmp[t] = a;
        __syncthreads();
        if (t < 8) {
            float o = ldw(zb2, t, f32);
            for (int j = 0; j < 64; j++) o += tmp[j] * ldw(zW2, j * 8 + t, f32);
            STORE_OUT(4352 + g * 8 + t, o);
        }
    }
#undef STORE_OUT
}

// ---------------- host ----------------

extern "C" void kernel_launch(void* const* d_in, const int* in_sizes, int n_in,
                              void* d_out, int out_size, void* d_ws, size_t ws_size,
                              hipStream_t stream) {
    const void* x     = d_in[0];
    const int*  ei    = (const int*)d_in[1];
    const int*  batch = (const int*)d_in[2];

    int N = in_sizes[0] / 128;
    int E = in_sizes[1] / 2;

    char* w = (char*)d_ws;
    float* A = (float*)w;          w += (size_t)N * 128 * 4;
    float* B = (float*)w;          w += (size_t)N * 128 * 4;
    float4* asad = (float4*)w;     w += (size_t)N * 16;
    int* counts = (int*)w;         w += (size_t)N * 4;
    int* offs = (int*)w;           w += (size_t)N * 4;
    int* cursor = (int*)w;         w += (size_t)N * 4;
    int* adj = (int*)w;            w += (size_t)E * 4;
    int* bsums = (int*)w;          w += 512 * 4;
    int* node0 = (int*)w;          w += 256 * 4;
    int* flag = (int*)w;           w += 64;

    int nb = (N + 255) / 256;

    k_zero<<<1, 64, 0, stream>>>(flag, 1);
    k_detect<<<16, 256, 0, stream>>>(x, flag);
    k_convert<<<(N * 128 + 255) / 256, 256, 0, stream>>>(x, A, N * 128, flag);
    k_zero<<<nb, 256, 0, stream>>>(counts, N);
    k_hist<<<(E + 255) / 256, 256, 0, stream>>>(ei, counts, E);
    k_scan1<<<nb, 256, 0, stream>>>(counts, offs, bsums, N);
    k_scan2<<<1, 512, 0, stream>>>(bsums, nb);
    k_scan3<<<nb, 256, 0, stream>>>(offs, cursor, bsums, N);
    k_scatter<<<(E + 255) / 256, 256, 0, stream>>>(ei, cursor, adj, E);
    k_node0<<<nb, 256, 0, stream>>>(batch, node0, N);

    for (int l = 0; l < 3; l++) {
        size_t wW = (size_t)l * 16384;  // element offsets
        size_t wa = (size_t)l * 128;
        k_gemm_bf16<<<(N + 31) / 32, 256, 0, stream>>>(A, d_in[3], wW, B, N, flag);
        k_gemm_f32 <<<(N + 31) / 32, 256, 0, stream>>>(A, d_in[3], wW, B, N, flag);
        k_asad<<<(N + 3) / 4, 256, 0, stream>>>(B, d_in[4], d_in[5], wa, asad, N, flag);
        k_agg<<<(N + 3) / 4, 256, 0, stream>>>(B, asad, offs, counts, adj,
                                               d_in[6], wa, A, N, (l < 2) ? 1 : 0, flag);
    }

    k_heads<<<256, 64, 0, stream>>>(A, x, node0,
                                    d_in[7], d_in[8], d_in[9], d_in[10], d_in[11], d_in[12],
                                    d_in[13], d_in[14], d_in[15], d_in[16],
                                    d_in[17], d_in[18], d_in[19], d_in[20],
                                    d_in[21], d_in[22], d_in[23], d_in[24],
                                    d_in[25], d_in[26], d_in[27], d_in[28],
                                    d_out, flag);
}

// Round 3
// 995.987 us; speedup vs baseline: 1.1660x; 1.1660x over previous
//
#include <hip/hip_runtime.h>
#include <hip/hip_bf16.h>

typedef __hip_bfloat16 bf16;
typedef __attribute__((ext_vector_type(8))) short short8;
typedef __attribute__((ext_vector_type(4))) float floatx4;

__device__ __forceinline__ float b2f(bf16 v) { return __bfloat162float(v); }
__device__ __forceinline__ float us2f(unsigned short u) {
    return __uint_as_float(((unsigned)u) << 16);
}
__device__ __forceinline__ unsigned short f2us(float f) {
    bf16 h = __float2bfloat16(f);
    return *(unsigned short*)&h;
}
__device__ __forceinline__ float leaky(float v) { return v > 0.f ? v : 0.2f * v; }

// flag-aware raw-input read by ELEMENT index: flag==1 -> f32 storage, else bf16
__device__ __forceinline__ float ldw(const void* p, size_t i, int f32) {
    return f32 ? ((const float*)p)[i] : b2f(((const bf16*)p)[i]);
}

// ---------------- dtype detection ----------------
__global__ void k_detect(const void* x, int* flag) {
    int i = blockIdx.x * blockDim.x + threadIdx.x;
    float v = b2f(((const bf16*)x)[i]);
    if (!(fabsf(v) < 1e10f)) atomicOr(flag, 1);  // NaN/inf/huge -> f32 storage
}

__global__ void k_zero(int* __restrict__ p, int n) {
    int i = blockIdx.x * blockDim.x + threadIdx.x;
    if (i < n) p[i] = 0;
}

// ---------------- prep: convert inputs to working formats ----------------
__global__ void k_prep_x(const void* __restrict__ x, unsigned short* __restrict__ Ab,
                         int n, const int* __restrict__ flag) {
    int i = blockIdx.x * 256 + threadIdx.x;
    int f32 = *flag;
    if (i < n) Ab[i] = f2us(ldw(x, i, f32));
}

// Wt[l][n][k] (bf16) from gat_W[l][k][n]
__global__ void k_prep_w(const void* __restrict__ gw, unsigned short* __restrict__ Wt,
                         const int* __restrict__ flag) {
    int i = blockIdx.x * 256 + threadIdx.x;  // i < 3*16384
    int f32 = *flag;
    int l = i >> 14, rem = i & 16383, n = rem >> 7, k = rem & 127;
    Wt[i] = f2us(ldw(gw, (size_t)l * 16384 + (size_t)k * 128 + n, f32));
}

__global__ void k_prep_small(const void* as_, const void* ad_, const void* b_,
                             float* asF, float* adF, float* bF,
                             const int* __restrict__ flag) {
    int i = blockIdx.x * blockDim.x + threadIdx.x;
    int f32 = *flag;
    if (i < 384) {
        asF[i] = ldw(as_, i, f32);
        adF[i] = ldw(ad_, i, f32);
        bF[i] = ldw(b_, i, f32);
    }
}

// ---------------- graph build ----------------
__global__ void k_hist(const int* __restrict__ ei, int* __restrict__ counts, int E) {
    int e = blockIdx.x * blockDim.x + threadIdx.x;
    if (e < E) atomicAdd(&counts[ei[E + e]], 1);
}

__global__ void k_scan1(const int* __restrict__ counts, int* __restrict__ offs,
                        int* __restrict__ bsums, int n) {
    __shared__ int s[256];
    int tid = threadIdx.x;
    int i = blockIdx.x * 256 + tid;
    int v = (i < n) ? counts[i] : 0;
    s[tid] = v;
    __syncthreads();
    for (int d = 1; d < 256; d <<= 1) {
        int t = (tid >= d) ? s[tid - d] : 0;
        __syncthreads();
        s[tid] += t;
        __syncthreads();
    }
    int incl = s[tid];
    if (i < n) offs[i] = incl - v;
    if (tid == 255) bsums[blockIdx.x] = incl;
}

__global__ void k_scan2(int* __restrict__ bsums, int nb) {
    __shared__ int s[512];
    int tid = threadIdx.x;
    int v = (tid < nb) ? bsums[tid] : 0;
    s[tid] = v;
    __syncthreads();
    for (int d = 1; d < 512; d <<= 1) {
        int t = (tid >= d) ? s[tid - d] : 0;
        __syncthreads();
        s[tid] += t;
        __syncthreads();
    }
    bsums[tid] = s[tid] - v;
}

__global__ void k_scan3(int* __restrict__ offs, int* __restrict__ cursor,
                        const int* __restrict__ bsums, int n) {
    int i = blockIdx.x * 256 + threadIdx.x;
    if (i < n) {
        int o = offs[i] + bsums[blockIdx.x];
        offs[i] = o;
        cursor[i] = o;
    }
}

__global__ void k_scatter(const int* __restrict__ ei, int* __restrict__ cursor,
                          int* __restrict__ adj, int E) {
    int e = blockIdx.x * blockDim.x + threadIdx.x;
    if (e < E) {
        int d = ei[E + e];
        int pos = atomicAdd(&cursor[d], 1);
        adj[pos] = ei[e];
    }
}

__global__ void k_node0(const int* __restrict__ batch, int* __restrict__ node0, int n) {
    int i = blockIdx.x * blockDim.x + threadIdx.x;
    if (i < n) {
        int b = batch[i];
        if (i == 0 || batch[i - 1] != b) node0[b] = i;
    }
}

// ---------------- MFMA GEMM + fused attention scalars ----------------
// B[N,128](bf16) = A[N,128](bf16) @ W[128,128]; asad[n] = (h.asrc h0/h1, h.adst h0/h1)
// block: 256 thr (4 waves), 64 rows; wave w: rows w*16..w*16+15, all 128 cols.
// A-frag (16x16x32): A[m=lane&15][k=quad*8+j]; B-frag: B[k=quad*8+j][n=lane&15]
// C/D: col=lane&15, row=quad*4+reg   [per cdna_hip_programming.md §3, m89/m91]
__global__ __launch_bounds__(256) void k_gemm_mfma(
    const unsigned short* __restrict__ Ab, const unsigned short* __restrict__ Wt,
    unsigned short* __restrict__ Bb, float4* __restrict__ asadv,
    const float* __restrict__ asF, const float* __restrict__ adF, int N) {
    __shared__ unsigned short As[64 * 136];  // +8 pad: 272B row stride -> 2-way max (free)

    int t = threadIdx.x;
    int r0 = blockIdx.x * 64;

    // stage A tile: 64 rows x 128 bf16, 16B chunks
    const short8* Ag = (const short8*)(Ab + (size_t)r0 * 128);
    for (int ch = t; ch < 1024; ch += 256) {
        int row = ch >> 4, c8 = ch & 15;
        *(short8*)&As[row * 136 + c8 * 8] = Ag[ch];
    }
    __syncthreads();

    int lane = t & 63;
    int w = t >> 6;
    int ln = lane & 15;
    int quad = lane >> 4;

    short8 afrag[4];
#pragma unroll
    for (int kt = 0; kt < 4; kt++)
        afrag[kt] = *(const short8*)&As[(w * 16 + ln) * 136 + kt * 32 + quad * 8];

    floatx4 acc[8];
#pragma unroll
    for (int nt = 0; nt < 8; nt++) acc[nt] = (floatx4){0.f, 0.f, 0.f, 0.f};

#pragma unroll
    for (int nt = 0; nt < 8; nt++) {
        const unsigned short* wp = Wt + (size_t)(nt * 16 + ln) * 128 + quad * 8;
#pragma unroll
        for (int kt = 0; kt < 4; kt++) {
            short8 bfrag = *(const short8*)(wp + kt * 32);
            acc[nt] = __builtin_amdgcn_mfma_f32_16x16x32_bf16(afrag[kt], bfrag, acc[nt], 0, 0, 0);
        }
    }

    // epilogue: store bf16 C + per-row attention scalars
    float as0[4] = {0, 0, 0, 0}, as1[4] = {0, 0, 0, 0};
    float ad0[4] = {0, 0, 0, 0}, ad1[4] = {0, 0, 0, 0};
#pragma unroll
    for (int nt = 0; nt < 8; nt++) {
        float asc = asF[nt * 16 + ln];
        float adc = adF[nt * 16 + ln];
#pragma unroll
        for (int r = 0; r < 4; r++) {
            float v = acc[nt][r];
            int row = r0 + w * 16 + quad * 4 + r;
            Bb[(size_t)row * 128 + nt * 16 + ln] = f2us(v);
            if (nt < 4) { as0[r] += v * asc; ad0[r] += v * adc; }
            else        { as1[r] += v * asc; ad1[r] += v * adc; }
        }
    }
#pragma unroll
    for (int mask = 1; mask <= 8; mask <<= 1) {
#pragma unroll
        for (int r = 0; r < 4; r++) {
            as0[r] += __shfl_xor(as0[r], mask);
            as1[r] += __shfl_xor(as1[r], mask);
            ad0[r] += __shfl_xor(ad0[r], mask);
            ad1[r] += __shfl_xor(ad1[r], mask);
        }
    }
    if (ln == 0) {
#pragma unroll
        for (int r = 0; r < 4; r++) {
            int row = r0 + w * 16 + quad * 4 + r;
            asadv[row] = make_float4(as0[r], as1[r], ad0[r], ad1[r]);
        }
    }
}

// ---------------- GAT aggregation: one wave per node, bf16 gathers ----------------
// lane handles channels 2*lane, 2*lane+1 (one dword of bf16x2); head = lane>>5
__global__ void k_agg2(const unsigned* __restrict__ Bu, const float* __restrict__ asadf,
                       const int* __restrict__ offs, const int* __restrict__ counts,
                       const int* __restrict__ adj, const float* __restrict__ biasF,
                       unsigned* __restrict__ Au, int n, int dorelu) {
    int node = (blockIdx.x * blockDim.x + threadIdx.x) >> 6;
    int lane = threadIdx.x & 63;
    if (node >= n) return;
    int head = lane >> 5;

    float ad = asadf[(size_t)node * 4 + 2 + head];
    float as_self = asadf[(size_t)node * 4 + head];
    float m = leaky(as_self + ad);
    float s = 1.f;
    unsigned hvs = Bu[(size_t)node * 64 + lane];
    float acc0 = us2f(hvs & 0xffff), acc1 = us2f(hvs >> 16);

    int o = offs[node], c = counts[node];
    // software pipeline: prefetch next neighbor's asad + features
    int src = (c > 0) ? adj[o] : 0;
    float av = asadf[(size_t)src * 4 + head];
    unsigned hv = Bu[(size_t)src * 64 + lane];

    for (int i = 0; i < c; i++) {
        float avc = av;
        unsigned hvc = hv;
        int nx = (i + 1 < c) ? i + 1 : i;
        int s2 = adj[o + nx];
        av = asadf[(size_t)s2 * 4 + head];
        hv = Bu[(size_t)s2 * 64 + lane];

        float e = leaky(avc + ad);
        float mn = fmaxf(m, e);
        float corr = __expf(m - mn);
        float p = __expf(e - mn);
        s = s * corr + p;
        float h0 = us2f(hvc & 0xffff), h1 = us2f(hvc >> 16);
        acc0 = acc0 * corr + p * h0;
        acc1 = acc1 * corr + p * h1;
        m = mn;
    }

    float inv = 1.f / (s + 1e-16f);
    int c0 = 2 * lane;
    float o0 = acc0 * inv + biasF[c0];
    float o1 = acc1 * inv + biasF[c0 + 1];
    if (dorelu) { o0 = fmaxf(o0, 0.f); o1 = fmaxf(o1, 0.f); }
    Au[(size_t)node * 64 + lane] = ((unsigned)f2us(o1) << 16) | f2us(o0);
}

// ---------------- heads: one wave per graph ----------------
__global__ __launch_bounds__(64) void k_heads(
    const unsigned short* __restrict__ Ab, const void* __restrict__ x,
    const int* __restrict__ node0,
    const void* sW, const void* sb,
    const void* pW1, const void* pb1, const void* pW2, const void* pb2,
    const void* cW1, const void* cb1, const void* cW2, const void* cb2,
    const void* fW1, const void* fb1, const void* fW2, const void* fb2,
    const void* bW1, const void* bb1, const void* bW2, const void* bb2,
    const void* zW1, const void* zb1, const void* zW2, const void* zb2,
    void* __restrict__ outv, const int* __restrict__ flag) {
    int g = blockIdx.x;
    int t = threadIdx.x;
    int f32 = *flag;
    bf16* outb = (bf16*)outv;
    float* outf = (float*)outv;
    __shared__ float in150[152];
    __shared__ float zf[64];
    __shared__ float tmp[64];
    __shared__ float bin[96];

#define STORE_OUT(idx, val) do { if (f32) outf[idx] = (val); else outb[idx] = __float2bfloat16(val); } while (0)

    int n0 = node0[g];
    in150[t] = us2f(Ab[(size_t)n0 * 128 + t]);
    in150[64 + t] = us2f(Ab[(size_t)n0 * 128 + 64 + t]);
    if (t < 22) in150[128 + t] = ldw(x, (size_t)n0 * 128 + t, f32);
    __syncthreads();

    {
        float a = ldw(sb, t, f32);
        for (int i = 0; i < 150; i++) a += in150[i] * ldw(sW, i * 64 + t, f32);
        a = fmaxf(a, 0.f);
        zf[t] = a;
        bin[t] = a;
        if (t < 22) bin[64 + t] = in150[128 + t];
    }
    __syncthreads();

    for (int k = 0; k < 3; k++) {
        float a = ldw(pb1, k * 64 + t, f32);
        for (int i = 0; i < 64; i++) a += zf[i] * ldw(pW1, k * 4096 + i * 64 + t, f32);
        a = fmaxf(a, 0.f);
        tmp[t] = a;
        __syncthreads();
        if (t < 3) {
            float o = ldw(pb2, k * 3 + t, f32);
            for (int j = 0; j < 64; j++) o += tmp[j] * ldw(pW2, k * 192 + j * 3 + t, f32);
            STORE_OUT(k * 768 + g * 3 + t, o);
        }
        __syncthreads();
    }

    {
        float a = ldw(cb1, t, f32);
        for (int i = 0; i < 64; i++) a += zf[i] * ldw(cW1, i * 64 + t, f32);
        a = fmaxf(a, 0.f);
        tmp[t] = a;
        __syncthreads();
        if (t < 5) {
            float o = ldw(cb2, t, f32);
            for (int j = 0; j < 64; j++) o += tmp[j] * ldw(cW2, j * 5 + t, f32);
            bin[86 + t] = o;
            STORE_OUT(2304 + g * 5 + t, o);
        }
        __syncthreads();
    }

    for (int k = 0; k < 2; k++) {
        float a = ldw(fb1, k * 64 + t, f32);
        for (int i = 0; i < 64; i++) a += zf[i] * ldw(fW1, k * 4096 + i * 64 + t, f32);
        a = fmaxf(a, 0.f);
        tmp[t] = a;
        __syncthreads();
        if (t == 0) {
            float o = ldw(fb2, k, f32);
            for (int j = 0; j < 64; j++) o += tmp[j] * ldw(fW2, k * 64 + j, f32);
            bin[91 + k] = o;
            STORE_OUT(3584 + k * 256 + g, o);
        }
        __syncthreads();
    }

    {
        float a = ldw(bb1, t, f32);
        for (int i = 0; i < 93; i++) a += bin[i] * ldw(bW1, i * 64 + t, f32);
        a = fmaxf(a, 0.f);
        tmp[t] = a;
        __syncthreads();
        if (t == 0) {
            float o = ldw(bb2, 0, f32);
            for (int j = 0; j < 64; j++) o += tmp[j] * ldw(bW2, j, f32);
            bin[93] = o;
            STORE_OUT(4096 + g, o);
        }
        __syncthreads();
    }

    {
        float a = ldw(zb1, t, f32);
        for (int i = 0; i < 94; i++) a += bin[i] * ldw(zW1, i * 64 + t, f32);
        a = fmaxf(a, 0.f);
        tmp[t] = a;
        __syncthreads();
        if (t < 8) {
            float o = ldw(zb2, t, f32);
            for (int j = 0; j < 64; j++) o += tmp[j] * ldw(zW2, j * 8 + t, f32);
            STORE_OUT(4352 + g * 8 + t, o);
        }
    }
#undef STORE_OUT
}

// ---------------- host ----------------

extern "C" void kernel_launch(void* const* d_in, const int* in_sizes, int n_in,
                              void* d_out, int out_size, void* d_ws, size_t ws_size,
                              hipStream_t stream) {
    const void* x     = d_in[0];
    const int*  ei    = (const int*)d_in[1];
    const int*  batch = (const int*)d_in[2];

    int N = in_sizes[0] / 128;
    int E = in_sizes[1] / 2;

    char* w = (char*)d_ws;
    float4* asad = (float4*)w;            w += (size_t)N * 16;
    unsigned short* A = (unsigned short*)w; w += (size_t)N * 128 * 2;
    unsigned short* B = (unsigned short*)w; w += (size_t)N * 128 * 2;
    unsigned short* Wt = (unsigned short*)w; w += 3 * 16384 * 2;
    float* asF = (float*)w;               w += 384 * 4;
    float* adF = (float*)w;               w += 384 * 4;
    float* bF = (float*)w;                w += 384 * 4;
    int* counts = (int*)w;                w += (size_t)N * 4;
    int* offs = (int*)w;                  w += (size_t)N * 4;
    int* cursor = (int*)w;                w += (size_t)N * 4;
    int* adj = (int*)w;                   w += (size_t)E * 4;
    int* bsums = (int*)w;                 w += 512 * 4;
    int* node0 = (int*)w;                 w += 256 * 4;
    int* flag = (int*)w;                  w += 64;

    int nb = (N + 255) / 256;

    k_zero<<<1, 64, 0, stream>>>(flag, 1);
    k_detect<<<16, 256, 0, stream>>>(x, flag);

    k_prep_x<<<(N * 128 + 255) / 256, 256, 0, stream>>>(x, A, N * 128, flag);
    k_prep_w<<<192, 256, 0, stream>>>(d_in[3], Wt, flag);
    k_prep_small<<<2, 256, 0, stream>>>(d_in[4], d_in[5], d_in[6], asF, adF, bF, flag);

    k_zero<<<nb, 256, 0, stream>>>(counts, N);
    k_hist<<<(E + 255) / 256, 256, 0, stream>>>(ei, counts, E);
    k_scan1<<<nb, 256, 0, stream>>>(counts, offs, bsums, N);
    k_scan2<<<1, 512, 0, stream>>>(bsums, nb);
    k_scan3<<<nb, 256, 0, stream>>>(offs, cursor, bsums, N);
    k_scatter<<<(E + 255) / 256, 256, 0, stream>>>(ei, cursor, adj, E);
    k_node0<<<nb, 256, 0, stream>>>(batch, node0, N);

    for (int l = 0; l < 3; l++) {
        k_gemm_mfma<<<(N + 63) / 64, 256, 0, stream>>>(
            A, Wt + (size_t)l * 16384, B, asad, asF + l * 128, adF + l * 128, N);
        k_agg2<<<(N + 3) / 4, 256, 0, stream>>>(
            (const unsigned*)B, (const float*)asad, offs, counts, adj,
            bF + l * 128, (unsigned*)A, N, (l < 2) ? 1 : 0);
    }

    k_heads<<<256, 64, 0, stream>>>(A, x, node0,
                                    d_in[7], d_in[8], d_in[9], d_in[10], d_in[11], d_in[12],
                                    d_in[13], d_in[14], d_in[15], d_in[16],
                                    d_in[17], d_in[18], d_in[19], d_in[20],
                                    d_in[21], d_in[22], d_in[23], d_in[24],
                                    d_in[25], d_in[26], d_in[27], d_in[28],
                                    d_out, flag);
}

// Round 4
// 876.373 us; speedup vs baseline: 1.3251x; 1.1365x over previous
//
#include <hip/hip_runtime.h>
#include <hip/hip_bf16.h>

typedef __hip_bfloat16 bf16;
typedef __attribute__((ext_vector_type(8))) short short8;
typedef __attribute__((ext_vector_type(4))) float floatx4;

__device__ __forceinline__ float b2f(bf16 v) { return __bfloat162float(v); }
__device__ __forceinline__ float us2f(unsigned short u) {
    return __uint_as_float(((unsigned)u) << 16);
}
__device__ __forceinline__ unsigned short f2us(float f) {
    bf16 h = __float2bfloat16(f);
    return *(unsigned short*)&h;
}
__device__ __forceinline__ float lo2f(unsigned hv) { return __uint_as_float(hv << 16); }
__device__ __forceinline__ float hi2f(unsigned hv) { return __uint_as_float(hv & 0xffff0000u); }
__device__ __forceinline__ float leaky(float v) { return v > 0.f ? v : 0.2f * v; }

// flag-aware raw-input read by ELEMENT index: flag==1 -> f32 storage, else bf16
__device__ __forceinline__ float ldw(const void* p, size_t i, int f32) {
    return f32 ? ((const float*)p)[i] : b2f(((const bf16*)p)[i]);
}

// ---------------- dtype detection ----------------
__global__ void k_detect(const void* x, int* flag) {
    int i = blockIdx.x * blockDim.x + threadIdx.x;
    float v = b2f(((const bf16*)x)[i]);
    if (!(fabsf(v) < 1e10f)) atomicOr(flag, 1);  // NaN/inf/huge -> f32 storage
}

__global__ void k_zero(int* __restrict__ p, int n) {
    int i = blockIdx.x * blockDim.x + threadIdx.x;
    if (i < n) p[i] = 0;
}

// ---------------- prep ----------------
__global__ void k_prep_x(const void* __restrict__ x, unsigned short* __restrict__ Ab,
                         int n, const int* __restrict__ flag) {
    int i = blockIdx.x * 256 + threadIdx.x;
    int f32 = *flag;
    if (i < n) Ab[i] = f2us(ldw(x, i, f32));
}

// Wt[l][n][k] (bf16) from gat_W[l][k][n]
__global__ void k_prep_w(const void* __restrict__ gw, unsigned short* __restrict__ Wt,
                         const int* __restrict__ flag) {
    int i = blockIdx.x * 256 + threadIdx.x;  // i < 3*16384
    int f32 = *flag;
    int l = i >> 14, rem = i & 16383, n = rem >> 7, k = rem & 127;
    Wt[i] = f2us(ldw(gw, (size_t)l * 16384 + (size_t)k * 128 + n, f32));
}

__global__ void k_prep_small(const void* as_, const void* ad_, const void* b_,
                             float* asF, float* adF, float* bF,
                             const int* __restrict__ flag) {
    int i = blockIdx.x * blockDim.x + threadIdx.x;
    int f32 = *flag;
    if (i < 384) {
        asF[i] = ldw(as_, i, f32);
        adF[i] = ldw(ad_, i, f32);
        bF[i] = ldw(b_, i, f32);
    }
}

// ---------------- graph build ----------------
__global__ void k_hist(const int* __restrict__ ei, int* __restrict__ counts, int E) {
    int e = blockIdx.x * blockDim.x + threadIdx.x;
    if (e < E) atomicAdd(&counts[ei[E + e]], 1);
}

__global__ void k_scan1(const int* __restrict__ counts, int* __restrict__ offs,
                        int* __restrict__ bsums, int n) {
    __shared__ int s[256];
    int tid = threadIdx.x;
    int i = blockIdx.x * 256 + tid;
    int v = (i < n) ? counts[i] : 0;
    s[tid] = v;
    __syncthreads();
    for (int d = 1; d < 256; d <<= 1) {
        int t = (tid >= d) ? s[tid - d] : 0;
        __syncthreads();
        s[tid] += t;
        __syncthreads();
    }
    int incl = s[tid];
    if (i < n) offs[i] = incl - v;
    if (tid == 255) bsums[blockIdx.x] = incl;
}

__global__ void k_scan2(int* __restrict__ bsums, int nb) {
    __shared__ int s[512];
    int tid = threadIdx.x;
    int v = (tid < nb) ? bsums[tid] : 0;
    s[tid] = v;
    __syncthreads();
    for (int d = 1; d < 512; d <<= 1) {
        int t = (tid >= d) ? s[tid - d] : 0;
        __syncthreads();
        s[tid] += t;
        __syncthreads();
    }
    bsums[tid] = s[tid] - v;
}

__global__ void k_scan3(int* __restrict__ offs, int* __restrict__ cursor,
                        const int* __restrict__ bsums, int n) {
    int i = blockIdx.x * 256 + threadIdx.x;
    if (i < n) {
        int o = offs[i] + bsums[blockIdx.x];
        offs[i] = o;
        cursor[i] = o;
    }
}

__global__ void k_scatter(const int* __restrict__ ei, int* __restrict__ cursor,
                          int* __restrict__ adj, int E) {
    int e = blockIdx.x * blockDim.x + threadIdx.x;
    if (e < E) {
        int d = ei[E + e];
        int pos = atomicAdd(&cursor[d], 1);
        adj[pos] = ei[e];
    }
}

__global__ void k_node0(const int* __restrict__ batch, int* __restrict__ node0, int n) {
    int i = blockIdx.x * blockDim.x + threadIdx.x;
    if (i < n) {
        int b = batch[i];
        if (i == 0 || batch[i - 1] != b) node0[b] = i;
    }
}

// ---------------- MFMA GEMM + fused attention scalars ----------------
// B[N,128](bf16) = A[N,128](bf16) @ W[128,128]; asad[n] = (as0,as1,ad0,ad1)
__global__ __launch_bounds__(256) void k_gemm_mfma(
    const unsigned short* __restrict__ Ab, const unsigned short* __restrict__ Wt,
    unsigned short* __restrict__ Bb, float4* __restrict__ asadv,
    const float* __restrict__ asF, const float* __restrict__ adF, int N) {
    __shared__ unsigned short As[64 * 136];  // staging + C-transpose buffer

    int t = threadIdx.x;
    int r0 = blockIdx.x * 64;

    // stage A tile: 64 rows x 128 bf16
    const short8* Ag = (const short8*)(Ab + (size_t)r0 * 128);
    for (int ch = t; ch < 1024; ch += 256) {
        int row = ch >> 4, c8 = ch & 15;
        *(short8*)&As[row * 136 + c8 * 8] = Ag[ch];
    }
    __syncthreads();

    int lane = t & 63;
    int w = t >> 6;
    int ln = lane & 15;
    int quad = lane >> 4;

    short8 afrag[4];
#pragma unroll
    for (int kt = 0; kt < 4; kt++)
        afrag[kt] = *(const short8*)&As[(w * 16 + ln) * 136 + kt * 32 + quad * 8];
    __syncthreads();  // As free for reuse after all waves grabbed afrags

    floatx4 acc[8];
#pragma unroll
    for (int nt = 0; nt < 8; nt++) acc[nt] = (floatx4){0.f, 0.f, 0.f, 0.f};

#pragma unroll
    for (int nt = 0; nt < 8; nt++) {
        const unsigned short* wp = Wt + (size_t)(nt * 16 + ln) * 128 + quad * 8;
#pragma unroll
        for (int kt = 0; kt < 4; kt++) {
            short8 bfrag = *(const short8*)(wp + kt * 32);
            acc[nt] = __builtin_amdgcn_mfma_f32_16x16x32_bf16(afrag[kt], bfrag, acc[nt], 0, 0, 0);
        }
    }

    // attention scalars from accumulators (C layout: col=ln, row=quad*4+r)
    float as0[4] = {0, 0, 0, 0}, as1[4] = {0, 0, 0, 0};
    float ad0[4] = {0, 0, 0, 0}, ad1[4] = {0, 0, 0, 0};
#pragma unroll
    for (int nt = 0; nt < 8; nt++) {
        float asc = asF[nt * 16 + ln];
        float adc = adF[nt * 16 + ln];
#pragma unroll
        for (int r = 0; r < 4; r++) {
            float v = acc[nt][r];
            // write C to LDS (bf16) for coalesced global store later
            As[(w * 16 + quad * 4 + r) * 136 + nt * 16 + ln] = f2us(v);
            if (nt < 4) { as0[r] += v * asc; ad0[r] += v * adc; }
            else        { as1[r] += v * asc; ad1[r] += v * adc; }
        }
    }
#pragma unroll
    for (int mask = 1; mask <= 8; mask <<= 1) {
#pragma unroll
        for (int r = 0; r < 4; r++) {
            as0[r] += __shfl_xor(as0[r], mask);
            as1[r] += __shfl_xor(as1[r], mask);
            ad0[r] += __shfl_xor(ad0[r], mask);
            ad1[r] += __shfl_xor(ad1[r], mask);
        }
    }
    if (ln == 0) {
#pragma unroll
        for (int r = 0; r < 4; r++) {
            int row = r0 + w * 16 + quad * 4 + r;
            asadv[row] = make_float4(as0[r], as1[r], ad0[r], ad1[r]);
        }
    }
    __syncthreads();

    // coalesced C store: 4 threads per row, each 32 shorts (4 x 16B)
    {
        int row = t >> 2;
        int cseg = (t & 3) * 32;
        const short8* srcp = (const short8*)&As[row * 136 + cseg];
        short8* dstp = (short8*)&Bb[(size_t)(r0 + row) * 128 + cseg];
#pragma unroll
        for (int u = 0; u < 4; u++) dstp[u] = srcp[u];
    }
}

// ---------------- GAT aggregation: one wave per node ----------------
// Phase 1 (lane-parallel): lane i computes p=exp(leaky(e)) for neighbor i.
// Phase 2 (gather): broadcast src/p via shfl, pure fma inner loop.
// No max-subtraction: e bounded for this model; alpha is scale-invariant.
__global__ void k_gat_agg(const unsigned* __restrict__ Bu, const float4* __restrict__ asadv,
                          const int* __restrict__ offs, const int* __restrict__ counts,
                          const int* __restrict__ adj, const float* __restrict__ biasF,
                          unsigned* __restrict__ Au, float2* __restrict__ pE,
                          int n, int dorelu) {
    int node = (blockIdx.x * blockDim.x + threadIdx.x) >> 6;
    int lane = threadIdx.x & 63;
    if (node >= n) return;
    int head = lane >> 5;

    float4 self = asadv[node];
    float ad0 = self.z, ad1 = self.w;
    float es0 = __expf(leaky(self.x + ad0));
    float es1 = __expf(leaky(self.y + ad1));

    int o = offs[node], c = counts[node];
    unsigned hvs = Bu[(size_t)node * 64 + lane];
    float acc0, acc1;

    if (c <= 64) {
        // ---- fast path: alphas in registers ----
        int src_r = 0;
        float p0 = 0.f, p1 = 0.f;
        if (lane < c) {
            src_r = adj[o + lane];
            float4 av = asadv[src_r];
            p0 = __expf(leaky(av.x + ad0));
            p1 = __expf(leaky(av.y + ad1));
        }
        float t0 = p0, t1 = p1;
#pragma unroll
        for (int mask = 1; mask <= 32; mask <<= 1) {
            t0 += __shfl_xor(t0, mask);
            t1 += __shfl_xor(t1, mask);
        }
        float inv0 = 1.f / (es0 + t0 + 1e-16f);
        float inv1 = 1.f / (es1 + t1 + 1e-16f);
        float invh = head ? inv1 : inv0;
        float aself = (head ? es1 : es0) * invh;
        acc0 = aself * lo2f(hvs);
        acc1 = aself * hi2f(hvs);

        int srcn = __shfl(src_r, 0);
        unsigned hv = 0;
        if (c > 0) hv = Bu[(size_t)srcn * 64 + lane];
        for (int i = 0; i < c; i++) {
            unsigned hvc = hv;
            float a0 = __shfl(p0, i);
            float a1 = __shfl(p1, i);
            int nx = (i + 1 < c) ? i + 1 : i;
            int s2 = __shfl(src_r, nx);
            if (i + 1 < c) hv = Bu[(size_t)s2 * 64 + lane];
            float a = (head ? a1 : a0) * invh;
            acc0 += a * lo2f(hvc);
            acc1 += a * hi2f(hvc);
        }
    } else {
        // ---- slow path (rare): p staged in global scratch ----
        float sum0 = es0, sum1 = es1;
        for (int base = 0; base < c; base += 64) {
            int i = base + lane;
            float p0 = 0.f, p1 = 0.f;
            if (i < c) {
                int s = adj[o + i];
                float4 av = asadv[s];
                p0 = __expf(leaky(av.x + ad0));
                p1 = __expf(leaky(av.y + ad1));
                pE[o + i] = make_float2(p0, p1);
            }
            float t0 = p0, t1 = p1;
#pragma unroll
            for (int mask = 1; mask <= 32; mask <<= 1) {
                t0 += __shfl_xor(t0, mask);
                t1 += __shfl_xor(t1, mask);
            }
            sum0 += t0; sum1 += t1;
        }
        float inv0 = 1.f / (sum0 + 1e-16f);
        float inv1 = 1.f / (sum1 + 1e-16f);
        float invh = head ? inv1 : inv0;
        float aself = (head ? es1 : es0) * invh;
        acc0 = aself * lo2f(hvs);
        acc1 = aself * hi2f(hvs);
        for (int i = 0; i < c; i++) {
            int s = adj[o + i];
            float2 pp = pE[o + i];
            unsigned hv = Bu[(size_t)s * 64 + lane];
            float a = (head ? pp.y : pp.x) * invh;
            acc0 += a * lo2f(hv);
            acc1 += a * hi2f(hv);
        }
    }

    float2 bb = ((const float2*)biasF)[lane];
    float o0 = acc0 + bb.x;
    float o1 = acc1 + bb.y;
    if (dorelu) { o0 = fmaxf(o0, 0.f); o1 = fmaxf(o1, 0.f); }
    Au[(size_t)node * 64 + lane] = ((unsigned)f2us(o1) << 16) | f2us(o0);
}

// ---------------- heads: one wave per graph ----------------
__global__ __launch_bounds__(64) void k_heads(
    const unsigned short* __restrict__ Ab, const void* __restrict__ x,
    const int* __restrict__ node0,
    const void* sW, const void* sb,
    const void* pW1, const void* pb1, const void* pW2, const void* pb2,
    const void* cW1, const void* cb1, const void* cW2, const void* cb2,
    const void* fW1, const void* fb1, const void* fW2, const void* fb2,
    const void* bW1, const void* bb1, const void* bW2, const void* bb2,
    const void* zW1, const void* zb1, const void* zW2, const void* zb2,
    void* __restrict__ outv, const int* __restrict__ flag) {
    int g = blockIdx.x;
    int t = threadIdx.x;
    int f32 = *flag;
    bf16* outb = (bf16*)outv;
    float* outf = (float*)outv;
    __shared__ float in150[152];
    __shared__ float zf[64];
    __shared__ float tmp[64];
    __shared__ float bin[96];

#define STORE_OUT(idx, val) do { if (f32) outf[idx] = (val); else outb[idx] = __float2bfloat16(val); } while (0)

    int n0 = node0[g];
    in150[t] = us2f(Ab[(size_t)n0 * 128 + t]);
    in150[64 + t] = us2f(Ab[(size_t)n0 * 128 + 64 + t]);
    if (t < 22) in150[128 + t] = ldw(x, (size_t)n0 * 128 + t, f32);
    __syncthreads();

    {
        float a = ldw(sb, t, f32);
        for (int i = 0; i < 150; i++) a += in150[i] * ldw(sW, i * 64 + t, f32);
        a = fmaxf(a, 0.f);
        zf[t] = a;
        bin[t] = a;
        if (t < 22) bin[64 + t] = in150[128 + t];
    }
    __syncthreads();

    for (int k = 0; k < 3; k++) {
        float a = ldw(pb1, k * 64 + t, f32);
        for (int i = 0; i < 64; i++) a += zf[i] * ldw(pW1, k * 4096 + i * 64 + t, f32);
        a = fmaxf(a, 0.f);
        tmp[t] = a;
        __syncthreads();
        if (t < 3) {
            float o = ldw(pb2, k * 3 + t, f32);
            for (int j = 0; j < 64; j++) o += tmp[j] * ldw(pW2, k * 192 + j * 3 + t, f32);
            STORE_OUT(k * 768 + g * 3 + t, o);
        }
        __syncthreads();
    }

    {
        float a = ldw(cb1, t, f32);
        for (int i = 0; i < 64; i++) a += zf[i] * ldw(cW1, i * 64 + t, f32);
        a = fmaxf(a, 0.f);
        tmp[t] = a;
        __syncthreads();
        if (t < 5) {
            float o = ldw(cb2, t, f32);
            for (int j = 0; j < 64; j++) o += tmp[j] * ldw(cW2, j * 5 + t, f32);
            bin[86 + t] = o;
            STORE_OUT(2304 + g * 5 + t, o);
        }
        __syncthreads();
    }

    for (int k = 0; k < 2; k++) {
        float a = ldw(fb1, k * 64 + t, f32);
        for (int i = 0; i < 64; i++) a += zf[i] * ldw(fW1, k * 4096 + i * 64 + t, f32);
        a = fmaxf(a, 0.f);
        tmp[t] = a;
        __syncthreads();
        if (t == 0) {
            float o = ldw(fb2, k, f32);
            for (int j = 0; j < 64; j++) o += tmp[j] * ldw(fW2, k * 64 + j, f32);
            bin[91 + k] = o;
            STORE_OUT(3584 + k * 256 + g, o);
        }
        __syncthreads();
    }

    {
        float a = ldw(bb1, t, f32);
        for (int i = 0; i < 93; i++) a += bin[i] * ldw(bW1, i * 64 + t, f32);
        a = fmaxf(a, 0.f);
        tmp[t] = a;
        __syncthreads();
        if (t == 0) {
            float o = ldw(bb2, 0, f32);
            for (int j = 0; j < 64; j++) o += tmp[j] * ldw(bW2, j, f32);
            bin[93] = o;
            STORE_OUT(4096 + g, o);
        }
        __syncthreads();
    }

    {
        float a = ldw(zb1, t, f32);
        for (int i = 0; i < 94; i++) a += bin[i] * ldw(zW1, i * 64 + t, f32);
        a = fmaxf(a, 0.f);
        tmp[t] = a;
        __syncthreads();
        if (t < 8) {
            float o = ldw(zb2, t, f32);
            for (int j = 0; j < 64; j++) o += tmp[j] * ldw(zW2, j * 8 + t, f32);
            STORE_OUT(4352 + g * 8 + t, o);
        }
    }
#undef STORE_OUT
}

// ---------------- host ----------------

extern "C" void kernel_launch(void* const* d_in, const int* in_sizes, int n_in,
                              void* d_out, int out_size, void* d_ws, size_t ws_size,
                              hipStream_t stream) {
    const void* x     = d_in[0];
    const int*  ei    = (const int*)d_in[1];
    const int*  batch = (const int*)d_in[2];

    int N = in_sizes[0] / 128;
    int E = in_sizes[1] / 2;

    char* w = (char*)d_ws;
    float4* asad = (float4*)w;              w += (size_t)N * 16;
    unsigned short* A = (unsigned short*)w; w += (size_t)N * 128 * 2;
    unsigned short* B = (unsigned short*)w; w += (size_t)N * 128 * 2;
    float2* pE = (float2*)w;                w += (size_t)E * 8;
    unsigned short* Wt = (unsigned short*)w; w += 3 * 16384 * 2;
    float* asF = (float*)w;                 w += 384 * 4;
    float* adF = (float*)w;                 w += 384 * 4;
    float* bF = (float*)w;                  w += 384 * 4;
    int* counts = (int*)w;                  w += (size_t)N * 4;
    int* offs = (int*)w;                    w += (size_t)N * 4;
    int* cursor = (int*)w;                  w += (size_t)N * 4;
    int* adj = (int*)w;                     w += (size_t)E * 4;
    int* bsums = (int*)w;                   w += 512 * 4;
    int* node0 = (int*)w;                   w += 256 * 4;
    int* flag = (int*)w;                    w += 64;

    int nb = (N + 255) / 256;

    k_zero<<<1, 64, 0, stream>>>(flag, 1);
    k_detect<<<16, 256, 0, stream>>>(x, flag);

    k_prep_x<<<(N * 128 + 255) / 256, 256, 0, stream>>>(x, A, N * 128, flag);
    k_prep_w<<<192, 256, 0, stream>>>(d_in[3], Wt, flag);
    k_prep_small<<<2, 256, 0, stream>>>(d_in[4], d_in[5], d_in[6], asF, adF, bF, flag);

    k_zero<<<nb, 256, 0, stream>>>(counts, N);
    k_hist<<<(E + 255) / 256, 256, 0, stream>>>(ei, counts, E);
    k_scan1<<<nb, 256, 0, stream>>>(counts, offs, bsums, N);
    k_scan2<<<1, 512, 0, stream>>>(bsums, nb);
    k_scan3<<<nb, 256, 0, stream>>>(offs, cursor, bsums, N);
    k_scatter<<<(E + 255) / 256, 256, 0, stream>>>(ei, cursor, adj, E);
    k_node0<<<nb, 256, 0, stream>>>(batch, node0, N);

    for (int l = 0; l < 3; l++) {
        k_gemm_mfma<<<(N + 63) / 64, 256, 0, stream>>>(
            A, Wt + (size_t)l * 16384, B, asad, asF + l * 128, adF + l * 128, N);
        k_gat_agg<<<(N + 3) / 4, 256, 0, stream>>>(
            (const unsigned*)B, asad, offs, counts, adj,
            bF + l * 128, (unsigned*)A, pE, N, (l < 2) ? 1 : 0);
    }

    k_heads<<<256, 64, 0, stream>>>(A, x, node0,
                                    d_in[7], d_in[8], d_in[9], d_in[10], d_in[11], d_in[12],
                                    d_in[13], d_in[14], d_in[15], d_in[16],
                                    d_in[17], d_in[18], d_in[19], d_in[20],
                                    d_in[21], d_in[22], d_in[23], d_in[24],
                                    d_in[25], d_in[26], d_in[27], d_in[28],
                                    d_out, flag);
}

// Round 5
// 807.725 us; speedup vs baseline: 1.4377x; 1.0850x over previous
//
#include <hip/hip_runtime.h>
#include <hip/hip_bf16.h>

typedef __hip_bfloat16 bf16;
typedef __attribute__((ext_vector_type(8))) short short8;
typedef __attribute__((ext_vector_type(4))) float floatx4;

__device__ __forceinline__ float b2f(bf16 v) { return __bfloat162float(v); }
__device__ __forceinline__ float us2f(unsigned short u) {
    return __uint_as_float(((unsigned)u) << 16);
}
__device__ __forceinline__ unsigned short f2us(float f) {
    bf16 h = __float2bfloat16(f);
    return *(unsigned short*)&h;
}
__device__ __forceinline__ float lo2f(unsigned hv) { return __uint_as_float(hv << 16); }
__device__ __forceinline__ float hi2f(unsigned hv) { return __uint_as_float(hv & 0xffff0000u); }
__device__ __forceinline__ float leaky(float v) { return v > 0.f ? v : 0.2f * v; }

// flag-aware raw-input read by ELEMENT index: flag==1 -> f32 storage, else bf16
__device__ __forceinline__ float ldw(const void* p, size_t i, int f32) {
    return f32 ? ((const float*)p)[i] : b2f(((const bf16*)p)[i]);
}

// ---------------- dtype detection ----------------
__global__ void k_detect(const void* x, int* flag) {
    int i = blockIdx.x * blockDim.x + threadIdx.x;
    float v = b2f(((const bf16*)x)[i]);
    if (!(fabsf(v) < 1e10f)) atomicOr(flag, 1);  // NaN/inf/huge -> f32 storage
}

__global__ void k_zero(int* __restrict__ p, int n) {
    int i = blockIdx.x * blockDim.x + threadIdx.x;
    if (i < n) p[i] = 0;
}

// ---------------- prep ----------------
__global__ void k_prep_x(const void* __restrict__ x, unsigned short* __restrict__ Ab,
                         int n, const int* __restrict__ flag) {
    int i = blockIdx.x * 256 + threadIdx.x;
    int f32 = *flag;
    if (i < n) Ab[i] = f2us(ldw(x, i, f32));
}

// Wt[l][n][k] (bf16) from gat_W[l][k][n]
__global__ void k_prep_w(const void* __restrict__ gw, unsigned short* __restrict__ Wt,
                         const int* __restrict__ flag) {
    int i = blockIdx.x * 256 + threadIdx.x;  // i < 3*16384
    int f32 = *flag;
    int l = i >> 14, rem = i & 16383, n = rem >> 7, k = rem & 127;
    Wt[i] = f2us(ldw(gw, (size_t)l * 16384 + (size_t)k * 128 + n, f32));
}

__global__ void k_prep_small(const void* as_, const void* ad_, const void* b_,
                             float* asF, float* adF, float* bF,
                             const int* __restrict__ flag) {
    int i = blockIdx.x * blockDim.x + threadIdx.x;
    int f32 = *flag;
    if (i < 384) {
        asF[i] = ldw(as_, i, f32);
        adF[i] = ldw(ad_, i, f32);
        bF[i] = ldw(b_, i, f32);
    }
}

// ---------------- graph build ----------------
__global__ void k_hist(const int* __restrict__ ei, int* __restrict__ counts, int E) {
    int e = blockIdx.x * blockDim.x + threadIdx.x;
    if (e < E) atomicAdd(&counts[ei[E + e]], 1);
}

__global__ void k_scan1(const int* __restrict__ counts, int* __restrict__ offs,
                        int* __restrict__ bsums, int n) {
    __shared__ int s[256];
    int tid = threadIdx.x;
    int i = blockIdx.x * 256 + tid;
    int v = (i < n) ? counts[i] : 0;
    s[tid] = v;
    __syncthreads();
    for (int d = 1; d < 256; d <<= 1) {
        int t = (tid >= d) ? s[tid - d] : 0;
        __syncthreads();
        s[tid] += t;
        __syncthreads();
    }
    int incl = s[tid];
    if (i < n) offs[i] = incl - v;
    if (tid == 255) bsums[blockIdx.x] = incl;
}

__global__ void k_scan2(int* __restrict__ bsums, int nb) {
    __shared__ int s[512];
    int tid = threadIdx.x;
    int v = (tid < nb) ? bsums[tid] : 0;
    s[tid] = v;
    __syncthreads();
    for (int d = 1; d < 512; d <<= 1) {
        int t = (tid >= d) ? s[tid - d] : 0;
        __syncthreads();
        s[tid] += t;
        __syncthreads();
    }
    bsums[tid] = s[tid] - v;
}

__global__ void k_scan3(int* __restrict__ offs, int* __restrict__ cursor,
                        const int* __restrict__ bsums, int n) {
    int i = blockIdx.x * 256 + threadIdx.x;
    if (i < n) {
        int o = offs[i] + bsums[blockIdx.x];
        offs[i] = o;
        cursor[i] = o;
    }
}

__global__ void k_scatter(const int* __restrict__ ei, int* __restrict__ cursor,
                          int* __restrict__ adj, int E) {
    int e = blockIdx.x * blockDim.x + threadIdx.x;
    if (e < E) {
        int d = ei[E + e];
        int pos = atomicAdd(&cursor[d], 1);
        adj[pos] = ei[e];
    }
}

__global__ void k_node0(const int* __restrict__ batch, int* __restrict__ node0, int n) {
    int i = blockIdx.x * blockDim.x + threadIdx.x;
    if (i < n) {
        int b = batch[i];
        if (i == 0 || batch[i - 1] != b) node0[b] = i;
    }
}

// ---------------- MFMA GEMM + fused attention scalars ----------------
__global__ __launch_bounds__(256) void k_gemm_mfma(
    const unsigned short* __restrict__ Ab, const unsigned short* __restrict__ Wt,
    unsigned short* __restrict__ Bb, float4* __restrict__ asadv,
    const float* __restrict__ asF, const float* __restrict__ adF, int N) {
    __shared__ unsigned short As[64 * 136];  // staging + C-transpose buffer

    int t = threadIdx.x;
    int r0 = blockIdx.x * 64;

    const short8* Ag = (const short8*)(Ab + (size_t)r0 * 128);
    for (int ch = t; ch < 1024; ch += 256) {
        int row = ch >> 4, c8 = ch & 15;
        *(short8*)&As[row * 136 + c8 * 8] = Ag[ch];
    }
    __syncthreads();

    int lane = t & 63;
    int w = t >> 6;
    int ln = lane & 15;
    int quad = lane >> 4;

    short8 afrag[4];
#pragma unroll
    for (int kt = 0; kt < 4; kt++)
        afrag[kt] = *(const short8*)&As[(w * 16 + ln) * 136 + kt * 32 + quad * 8];
    __syncthreads();

    floatx4 acc[8];
#pragma unroll
    for (int nt = 0; nt < 8; nt++) acc[nt] = (floatx4){0.f, 0.f, 0.f, 0.f};

#pragma unroll
    for (int nt = 0; nt < 8; nt++) {
        const unsigned short* wp = Wt + (size_t)(nt * 16 + ln) * 128 + quad * 8;
#pragma unroll
        for (int kt = 0; kt < 4; kt++) {
            short8 bfrag = *(const short8*)(wp + kt * 32);
            acc[nt] = __builtin_amdgcn_mfma_f32_16x16x32_bf16(afrag[kt], bfrag, acc[nt], 0, 0, 0);
        }
    }

    float as0[4] = {0, 0, 0, 0}, as1[4] = {0, 0, 0, 0};
    float ad0[4] = {0, 0, 0, 0}, ad1[4] = {0, 0, 0, 0};
#pragma unroll
    for (int nt = 0; nt < 8; nt++) {
        float asc = asF[nt * 16 + ln];
        float adc = adF[nt * 16 + ln];
#pragma unroll
        for (int r = 0; r < 4; r++) {
            float v = acc[nt][r];
            As[(w * 16 + quad * 4 + r) * 136 + nt * 16 + ln] = f2us(v);
            if (nt < 4) { as0[r] += v * asc; ad0[r] += v * adc; }
            else        { as1[r] += v * asc; ad1[r] += v * adc; }
        }
    }
#pragma unroll
    for (int mask = 1; mask <= 8; mask <<= 1) {
#pragma unroll
        for (int r = 0; r < 4; r++) {
            as0[r] += __shfl_xor(as0[r], mask);
            as1[r] += __shfl_xor(as1[r], mask);
            ad0[r] += __shfl_xor(ad0[r], mask);
            ad1[r] += __shfl_xor(ad1[r], mask);
        }
    }
    if (ln == 0) {
#pragma unroll
        for (int r = 0; r < 4; r++) {
            int row = r0 + w * 16 + quad * 4 + r;
            asadv[row] = make_float4(as0[r], as1[r], ad0[r], ad1[r]);
        }
    }
    __syncthreads();

    {
        int row = t >> 2;
        int cseg = (t & 3) * 32;
        const short8* srcp = (const short8*)&As[row * 136 + cseg];
        short8* dstp = (short8*)&Bb[(size_t)(r0 + row) * 128 + cseg];
#pragma unroll
        for (int u = 0; u < 4; u++) dstp[u] = srcp[u];
    }
}

// ---------------- GAT aggregation: one wave per node ----------------
__global__ void k_gat_agg(const unsigned* __restrict__ Bu, const float4* __restrict__ asadv,
                          const int* __restrict__ offs, const int* __restrict__ counts,
                          const int* __restrict__ adj, const float* __restrict__ biasF,
                          unsigned* __restrict__ Au, float2* __restrict__ pE,
                          int n, int dorelu) {
    int node = (blockIdx.x * blockDim.x + threadIdx.x) >> 6;
    int lane = threadIdx.x & 63;
    if (node >= n) return;
    int head = lane >> 5;

    float4 self = asadv[node];
    float ad0 = self.z, ad1 = self.w;
    float es0 = __expf(leaky(self.x + ad0));
    float es1 = __expf(leaky(self.y + ad1));

    int o = offs[node], c = counts[node];
    unsigned hvs = Bu[(size_t)node * 64 + lane];
    float acc0, acc1;

    if (c <= 64) {
        int src_r = 0;
        float p0 = 0.f, p1 = 0.f;
        if (lane < c) {
            src_r = adj[o + lane];
            float4 av = asadv[src_r];
            p0 = __expf(leaky(av.x + ad0));
            p1 = __expf(leaky(av.y + ad1));
        }
        float t0 = p0, t1 = p1;
#pragma unroll
        for (int mask = 1; mask <= 32; mask <<= 1) {
            t0 += __shfl_xor(t0, mask);
            t1 += __shfl_xor(t1, mask);
        }
        float inv0 = 1.f / (es0 + t0 + 1e-16f);
        float inv1 = 1.f / (es1 + t1 + 1e-16f);
        float invh = head ? inv1 : inv0;
        float aself = (head ? es1 : es0) * invh;
        acc0 = aself * lo2f(hvs);
        acc1 = aself * hi2f(hvs);

        int srcn = __shfl(src_r, 0);
        unsigned hv = 0;
        if (c > 0) hv = Bu[(size_t)srcn * 64 + lane];
        for (int i = 0; i < c; i++) {
            unsigned hvc = hv;
            float a0 = __shfl(p0, i);
            float a1 = __shfl(p1, i);
            int nx = (i + 1 < c) ? i + 1 : i;
            int s2 = __shfl(src_r, nx);
            if (i + 1 < c) hv = Bu[(size_t)s2 * 64 + lane];
            float a = (head ? a1 : a0) * invh;
            acc0 += a * lo2f(hvc);
            acc1 += a * hi2f(hvc);
        }
    } else {
        float sum0 = es0, sum1 = es1;
        for (int base = 0; base < c; base += 64) {
            int i = base + lane;
            float p0 = 0.f, p1 = 0.f;
            if (i < c) {
                int s = adj[o + i];
                float4 av = asadv[s];
                p0 = __expf(leaky(av.x + ad0));
                p1 = __expf(leaky(av.y + ad1));
                pE[o + i] = make_float2(p0, p1);
            }
            float t0 = p0, t1 = p1;
#pragma unroll
            for (int mask = 1; mask <= 32; mask <<= 1) {
                t0 += __shfl_xor(t0, mask);
                t1 += __shfl_xor(t1, mask);
            }
            sum0 += t0; sum1 += t1;
        }
        float inv0 = 1.f / (sum0 + 1e-16f);
        float inv1 = 1.f / (sum1 + 1e-16f);
        float invh = head ? inv1 : inv0;
        float aself = (head ? es1 : es0) * invh;
        acc0 = aself * lo2f(hvs);
        acc1 = aself * hi2f(hvs);
        for (int i = 0; i < c; i++) {
            int s = adj[o + i];
            float2 pp = pE[o + i];
            unsigned hv = Bu[(size_t)s * 64 + lane];
            float a = (head ? pp.y : pp.x) * invh;
            acc0 += a * lo2f(hv);
            acc1 += a * hi2f(hv);
        }
    }

    float2 bb = ((const float2*)biasF)[lane];
    float o0 = acc0 + bb.x;
    float o1 = acc1 + bb.y;
    if (dorelu) { o0 = fmaxf(o0, 0.f); o1 = fmaxf(o1, 0.f); }
    Au[(size_t)node * 64 + lane] = ((unsigned)f2us(o1) << 16) | f2us(o0);
}

// ---------------- heads: one block (4 waves) per graph ----------------
// K-reductions split across 4 waves (partial sums in LDS); tiny output layers
// use one-wave-per-output butterfly reductions. Cuts the serial dependent-load
// chain ~4x and gives 4 waves/CU instead of 1.
__global__ __launch_bounds__(256) void k_heads(
    const unsigned short* __restrict__ Ab, const void* __restrict__ x,
    const int* __restrict__ node0,
    const void* sW, const void* sb,
    const void* pW1, const void* pb1, const void* pW2, const void* pb2,
    const void* cW1, const void* cb1, const void* cW2, const void* cb2,
    const void* fW1, const void* fb1, const void* fW2, const void* fb2,
    const void* bW1, const void* bb1, const void* bW2, const void* bb2,
    const void* zW1, const void* zb1, const void* zW2, const void* zb2,
    void* __restrict__ outv, const int* __restrict__ flag) {
    int g = blockIdx.x;
    int t = threadIdx.x;
    int w = t >> 6;
    int lane = t & 63;
    int f32 = *flag;
    bf16* outb = (bf16*)outv;
    float* outf = (float*)outv;
    __shared__ float in150[152];
    __shared__ float part[4][64];
    __shared__ float zf[64];
    __shared__ float tmp[64];
    __shared__ float bin[96];

#define STORE_OUT(idx, val) do { if (f32) outf[idx] = (val); else outb[idx] = __float2bfloat16(val); } while (0)

    int n0 = node0[g];
    if (t < 128) in150[t] = us2f(Ab[(size_t)n0 * 128 + t]);
    else if (t < 150) in150[t] = ldw(x, (size_t)n0 * 128 + (t - 128), f32);
    __syncthreads();
    // dtype slice of bin
    if (t >= 64 && t < 86) bin[t] = in150[128 + (t - 64)];

    // ---- zf = relu([h||dtype] @ sW + sb), K=150 split 4 ways ----
    {
        int i0 = w * 38, i1 = min(150, i0 + 38);
        float p = 0.f;
        for (int i = i0; i < i1; i++) p += in150[i] * ldw(sW, (size_t)i * 64 + lane, f32);
        part[w][lane] = p;
    }
    __syncthreads();
    if (w == 0) {
        float a = part[0][lane] + part[1][lane] + part[2][lane] + part[3][lane]
                + ldw(sb, lane, f32);
        a = fmaxf(a, 0.f);
        zf[lane] = a;
        bin[lane] = a;
    }
    __syncthreads();

    // ---- ptr heads k=0..2: hidden(64,K=64) + out(3) ----
    for (int k = 0; k < 3; k++) {
        {
            int i0 = w * 16;
            float p = 0.f;
            for (int i = i0; i < i0 + 16; i++)
                p += zf[i] * ldw(pW1, (size_t)k * 4096 + (size_t)i * 64 + lane, f32);
            part[w][lane] = p;
        }
        __syncthreads();
        if (w == 0) {
            float a = part[0][lane] + part[1][lane] + part[2][lane] + part[3][lane]
                    + ldw(pb1, k * 64 + lane, f32);
            tmp[lane] = fmaxf(a, 0.f);
        }
        __syncthreads();
        if (w < 3) {
            float v = tmp[lane] * ldw(pW2, (size_t)k * 192 + (size_t)lane * 3 + w, f32);
#pragma unroll
            for (int mask = 1; mask <= 32; mask <<= 1) v += __shfl_xor(v, mask);
            if (lane == 0) STORE_OUT(k * 768 + g * 3 + w, v + ldw(pb2, k * 3 + w, f32));
        }
        __syncthreads();
    }

    // ---- cat: hidden(64,K=64) + out(5) ----
    {
        int i0 = w * 16;
        float p = 0.f;
        for (int i = i0; i < i0 + 16; i++)
            p += zf[i] * ldw(cW1, (size_t)i * 64 + lane, f32);
        part[w][lane] = p;
    }
    __syncthreads();
    if (w == 0) {
        float a = part[0][lane] + part[1][lane] + part[2][lane] + part[3][lane]
                + ldw(cb1, lane, f32);
        tmp[lane] = fmaxf(a, 0.f);
    }
    __syncthreads();
    for (int base = 0; base < 5; base += 4) {
        int o = base + w;
        if (o < 5) {
            float v = tmp[lane] * ldw(cW2, (size_t)lane * 5 + o, f32);
#pragma unroll
            for (int mask = 1; mask <= 32; mask <<= 1) v += __shfl_xor(v, mask);
            if (lane == 0) {
                float r = v + ldw(cb2, o, f32);
                bin[86 + o] = r;
                STORE_OUT(2304 + g * 5 + o, r);
            }
        }
        __syncthreads();
    }

    // ---- sf heads k=0,1: hidden(64,K=64) + out(1) ----
    for (int k = 0; k < 2; k++) {
        {
            int i0 = w * 16;
            float p = 0.f;
            for (int i = i0; i < i0 + 16; i++)
                p += zf[i] * ldw(fW1, (size_t)k * 4096 + (size_t)i * 64 + lane, f32);
            part[w][lane] = p;
        }
        __syncthreads();
        if (w == 0) {
            float a = part[0][lane] + part[1][lane] + part[2][lane] + part[3][lane]
                    + ldw(fb1, k * 64 + lane, f32);
            tmp[lane] = fmaxf(a, 0.f);
        }
        __syncthreads();
        if (w == 0) {
            float v = tmp[lane] * ldw(fW2, k * 64 + lane, f32);
#pragma unroll
            for (int mask = 1; mask <= 32; mask <<= 1) v += __shfl_xor(v, mask);
            if (lane == 0) {
                float r = v + ldw(fb2, k, f32);
                bin[91 + k] = r;
                STORE_OUT(3584 + k * 256 + g, r);
            }
        }
        __syncthreads();
    }

    // ---- bool: hidden(64,K=93) + out(1) ----
    {
        int i0 = w * 24, i1 = min(93, i0 + 24);
        float p = 0.f;
        for (int i = i0; i < i1; i++) p += bin[i] * ldw(bW1, (size_t)i * 64 + lane, f32);
        part[w][lane] = p;
    }
    __syncthreads();
    if (w == 0) {
        float a = part[0][lane] + part[1][lane] + part[2][lane] + part[3][lane]
                + ldw(bb1, lane, f32);
        tmp[lane] = fmaxf(a, 0.f);
    }
    __syncthreads();
    if (w == 0) {
        float v = tmp[lane] * ldw(bW2, lane, f32);
#pragma unroll
        for (int mask = 1; mask <= 32; mask <<= 1) v += __shfl_xor(v, mask);
        if (lane == 0) {
            float r = v + ldw(bb2, 0, f32);
            bin[93] = r;
            STORE_OUT(4096 + g, r);
        }
    }
    __syncthreads();

    // ---- size: hidden(64,K=94) + out(8) ----
    {
        int i0 = w * 24, i1 = min(94, i0 + 24);
        float p = 0.f;
        for (int i = i0; i < i1; i++) p += bin[i] * ldw(zW1, (size_t)i * 64 + lane, f32);
        part[w][lane] = p;
    }
    __syncthreads();
    if (w == 0) {
        float a = part[0][lane] + part[1][lane] + part[2][lane] + part[3][lane]
                + ldw(zb1, lane, f32);
        tmp[lane] = fmaxf(a, 0.f);
    }
    __syncthreads();
    for (int base = 0; base < 8; base += 4) {
        int o = base + w;
        float v = tmp[lane] * ldw(zW2, (size_t)lane * 8 + o, f32);
#pragma unroll
        for (int mask = 1; mask <= 32; mask <<= 1) v += __shfl_xor(v, mask);
        if (lane == 0) STORE_OUT(4352 + g * 8 + o, v + ldw(zb2, o, f32));
    }
#undef STORE_OUT
}

// ---------------- host ----------------

extern "C" void kernel_launch(void* const* d_in, const int* in_sizes, int n_in,
                              void* d_out, int out_size, void* d_ws, size_t ws_size,
                              hipStream_t stream) {
    const void* x     = d_in[0];
    const int*  ei    = (const int*)d_in[1];
    const int*  batch = (const int*)d_in[2];

    int N = in_sizes[0] / 128;
    int E = in_sizes[1] / 2;

    char* w = (char*)d_ws;
    float4* asad = (float4*)w;              w += (size_t)N * 16;
    unsigned short* A = (unsigned short*)w; w += (size_t)N * 128 * 2;
    unsigned short* B = (unsigned short*)w; w += (size_t)N * 128 * 2;
    float2* pE = (float2*)w;                w += (size_t)E * 8;
    unsigned short* Wt = (unsigned short*)w; w += 3 * 16384 * 2;
    float* asF = (float*)w;                 w += 384 * 4;
    float* adF = (float*)w;                 w += 384 * 4;
    float* bF = (float*)w;                  w += 384 * 4;
    int* counts = (int*)w;                  w += (size_t)N * 4;
    int* offs = (int*)w;                    w += (size_t)N * 4;
    int* cursor = (int*)w;                  w += (size_t)N * 4;
    int* adj = (int*)w;                     w += (size_t)E * 4;
    int* bsums = (int*)w;                   w += 512 * 4;
    int* node0 = (int*)w;                   w += 256 * 4;
    int* flag = (int*)w;                    w += 64;

    int nb = (N + 255) / 256;

    k_zero<<<1, 64, 0, stream>>>(flag, 1);
    k_detect<<<16, 256, 0, stream>>>(x, flag);

    k_prep_x<<<(N * 128 + 255) / 256, 256, 0, stream>>>(x, A, N * 128, flag);
    k_prep_w<<<192, 256, 0, stream>>>(d_in[3], Wt, flag);
    k_prep_small<<<2, 256, 0, stream>>>(d_in[4], d_in[5], d_in[6], asF, adF, bF, flag);

    k_zero<<<nb, 256, 0, stream>>>(counts, N);
    k_hist<<<(E + 255) / 256, 256, 0, stream>>>(ei, counts, E);
    k_scan1<<<nb, 256, 0, stream>>>(counts, offs, bsums, N);
    k_scan2<<<1, 512, 0, stream>>>(bsums, nb);
    k_scan3<<<nb, 256, 0, stream>>>(offs, cursor, bsums, N);
    k_scatter<<<(E + 255) / 256, 256, 0, stream>>>(ei, cursor, adj, E);
    k_node0<<<nb, 256, 0, stream>>>(batch, node0, N);

    for (int l = 0; l < 3; l++) {
        k_gemm_mfma<<<(N + 63) / 64, 256, 0, stream>>>(
            A, Wt + (size_t)l * 16384, B, asad, asF + l * 128, adF + l * 128, N);
        k_gat_agg<<<(N + 3) / 4, 256, 0, stream>>>(
            (const unsigned*)B, asad, offs, counts, adj,
            bF + l * 128, (unsigned*)A, pE, N, (l < 2) ? 1 : 0);
    }

    k_heads<<<256, 256, 0, stream>>>(A, x, node0,
                                     d_in[7], d_in[8], d_in[9], d_in[10], d_in[11], d_in[12],
                                     d_in[13], d_in[14], d_in[15], d_in[16],
                                     d_in[17], d_in[18], d_in[19], d_in[20],
                                     d_in[21], d_in[22], d_in[23], d_in[24],
                                     d_in[25], d_in[26], d_in[27], d_in[28],
                                     d_out, flag);
}

// Round 6
// 688.674 us; speedup vs baseline: 1.6863x; 1.1729x over previous
//
#include <hip/hip_runtime.h>
#include <hip/hip_bf16.h>

typedef __hip_bfloat16 bf16;
typedef __attribute__((ext_vector_type(8))) short short8;
typedef __attribute__((ext_vector_type(4))) float floatx4;

__device__ __forceinline__ float b2f(bf16 v) { return __bfloat162float(v); }
__device__ __forceinline__ float us2f(unsigned short u) {
    return __uint_as_float(((unsigned)u) << 16);
}
__device__ __forceinline__ unsigned short f2us(float f) {
    bf16 h = __float2bfloat16(f);
    return *(unsigned short*)&h;
}
__device__ __forceinline__ float lo2f(unsigned hv) { return __uint_as_float(hv << 16); }
__device__ __forceinline__ float hi2f(unsigned hv) { return __uint_as_float(hv & 0xffff0000u); }
__device__ __forceinline__ float leaky(float v) { return v > 0.f ? v : 0.2f * v; }

// flag-aware raw-input read by ELEMENT index: flag==1 -> f32 storage, else bf16
__device__ __forceinline__ float ldw(const void* p, size_t i, int f32) {
    return f32 ? ((const float*)p)[i] : b2f(((const bf16*)p)[i]);
}

// ---------------- dtype detection ----------------
__global__ void k_detect(const void* x, int* flag) {
    int i = blockIdx.x * blockDim.x + threadIdx.x;
    float v = b2f(((const bf16*)x)[i]);
    if (!(fabsf(v) < 1e10f)) atomicOr(flag, 1);  // NaN/inf/huge -> f32 storage
}

__global__ void k_zero(int* __restrict__ p, int n) {
    int i = blockIdx.x * blockDim.x + threadIdx.x;
    if (i < n) p[i] = 0;
}

// ---------------- prep ----------------
__global__ void k_prep_x(const void* __restrict__ x, unsigned short* __restrict__ Ab,
                         int n, const int* __restrict__ flag) {
    int i = blockIdx.x * 256 + threadIdx.x;
    int f32 = *flag;
    if (i < n) Ab[i] = f2us(ldw(x, i, f32));
}

// Wt[l][n][k] (bf16) from gat_W[l][k][n]
__global__ void k_prep_w(const void* __restrict__ gw, unsigned short* __restrict__ Wt,
                         const int* __restrict__ flag) {
    int i = blockIdx.x * 256 + threadIdx.x;  // i < 3*16384
    int f32 = *flag;
    int l = i >> 14, rem = i & 16383, n = rem >> 7, k = rem & 127;
    Wt[i] = f2us(ldw(gw, (size_t)l * 16384 + (size_t)k * 128 + n, f32));
}

__global__ void k_prep_small(const void* as_, const void* ad_, const void* b_,
                             float* asF, float* adF, float* bF,
                             const int* __restrict__ flag) {
    int i = blockIdx.x * blockDim.x + threadIdx.x;
    int f32 = *flag;
    if (i < 384) {
        asF[i] = ldw(as_, i, f32);
        adF[i] = ldw(ad_, i, f32);
        bF[i] = ldw(b_, i, f32);
    }
}

// ---------------- graph build ----------------
__global__ void k_hist(const int* __restrict__ ei, int* __restrict__ counts, int E) {
    int e = blockIdx.x * blockDim.x + threadIdx.x;
    if (e < E) atomicAdd(&counts[ei[E + e]], 1);
}

__global__ void k_scan1(const int* __restrict__ counts, int* __restrict__ offs,
                        int* __restrict__ bsums, int n) {
    __shared__ int s[256];
    int tid = threadIdx.x;
    int i = blockIdx.x * 256 + tid;
    int v = (i < n) ? counts[i] : 0;
    s[tid] = v;
    __syncthreads();
    for (int d = 1; d < 256; d <<= 1) {
        int t = (tid >= d) ? s[tid - d] : 0;
        __syncthreads();
        s[tid] += t;
        __syncthreads();
    }
    int incl = s[tid];
    if (i < n) offs[i] = incl - v;
    if (tid == 255) bsums[blockIdx.x] = incl;
}

__global__ void k_scan2(int* __restrict__ bsums, int nb) {
    __shared__ int s[512];
    int tid = threadIdx.x;
    int v = (tid < nb) ? bsums[tid] : 0;
    s[tid] = v;
    __syncthreads();
    for (int d = 1; d < 512; d <<= 1) {
        int t = (tid >= d) ? s[tid - d] : 0;
        __syncthreads();
        s[tid] += t;
        __syncthreads();
    }
    bsums[tid] = s[tid] - v;
}

__global__ void k_scan3(int* __restrict__ offs, int* __restrict__ cursor,
                        const int* __restrict__ bsums, int n) {
    int i = blockIdx.x * 256 + threadIdx.x;
    if (i < n) {
        int o = offs[i] + bsums[blockIdx.x];
        offs[i] = o;
        cursor[i] = o;
    }
}

__global__ void k_scatter(const int* __restrict__ ei, int* __restrict__ cursor,
                          int* __restrict__ adj, int E) {
    int e = blockIdx.x * blockDim.x + threadIdx.x;
    if (e < E) {
        int d = ei[E + e];
        int pos = atomicAdd(&cursor[d], 1);
        adj[pos] = ei[e];
    }
}

__global__ void k_node0(const int* __restrict__ batch, int* __restrict__ node0, int n) {
    int i = blockIdx.x * blockDim.x + threadIdx.x;
    if (i < n) {
        int b = batch[i];
        if (i == 0 || batch[i - 1] != b) node0[b] = i;
    }
}

// ---------------- MFMA GEMM + fused attention scalars ----------------
__global__ __launch_bounds__(256) void k_gemm_mfma(
    const unsigned short* __restrict__ Ab, const unsigned short* __restrict__ Wt,
    unsigned short* __restrict__ Bb, float4* __restrict__ asadv,
    const float* __restrict__ asF, const float* __restrict__ adF, int N) {
    __shared__ unsigned short As[64 * 136];  // staging + C-transpose buffer

    int t = threadIdx.x;
    int r0 = blockIdx.x * 64;

    const short8* Ag = (const short8*)(Ab + (size_t)r0 * 128);
    for (int ch = t; ch < 1024; ch += 256) {
        int row = ch >> 4, c8 = ch & 15;
        *(short8*)&As[row * 136 + c8 * 8] = Ag[ch];
    }
    __syncthreads();

    int lane = t & 63;
    int w = t >> 6;
    int ln = lane & 15;
    int quad = lane >> 4;

    short8 afrag[4];
#pragma unroll
    for (int kt = 0; kt < 4; kt++)
        afrag[kt] = *(const short8*)&As[(w * 16 + ln) * 136 + kt * 32 + quad * 8];
    __syncthreads();

    floatx4 acc[8];
#pragma unroll
    for (int nt = 0; nt < 8; nt++) acc[nt] = (floatx4){0.f, 0.f, 0.f, 0.f};

#pragma unroll
    for (int nt = 0; nt < 8; nt++) {
        const unsigned short* wp = Wt + (size_t)(nt * 16 + ln) * 128 + quad * 8;
#pragma unroll
        for (int kt = 0; kt < 4; kt++) {
            short8 bfrag = *(const short8*)(wp + kt * 32);
            acc[nt] = __builtin_amdgcn_mfma_f32_16x16x32_bf16(afrag[kt], bfrag, acc[nt], 0, 0, 0);
        }
    }

    float as0[4] = {0, 0, 0, 0}, as1[4] = {0, 0, 0, 0};
    float ad0[4] = {0, 0, 0, 0}, ad1[4] = {0, 0, 0, 0};
#pragma unroll
    for (int nt = 0; nt < 8; nt++) {
        float asc = asF[nt * 16 + ln];
        float adc = adF[nt * 16 + ln];
#pragma unroll
        for (int r = 0; r < 4; r++) {
            float v = acc[nt][r];
            As[(w * 16 + quad * 4 + r) * 136 + nt * 16 + ln] = f2us(v);
            if (nt < 4) { as0[r] += v * asc; ad0[r] += v * adc; }
            else        { as1[r] += v * asc; ad1[r] += v * adc; }
        }
    }
#pragma unroll
    for (int mask = 1; mask <= 8; mask <<= 1) {
#pragma unroll
        for (int r = 0; r < 4; r++) {
            as0[r] += __shfl_xor(as0[r], mask);
            as1[r] += __shfl_xor(as1[r], mask);
            ad0[r] += __shfl_xor(ad0[r], mask);
            ad1[r] += __shfl_xor(ad1[r], mask);
        }
    }
    if (ln == 0) {
#pragma unroll
        for (int r = 0; r < 4; r++) {
            int row = r0 + w * 16 + quad * 4 + r;
            asadv[row] = make_float4(as0[r], as1[r], ad0[r], ad1[r]);
        }
    }
    __syncthreads();

    {
        int row = t >> 2;
        int cseg = (t & 3) * 32;
        const short8* srcp = (const short8*)&As[row * 136 + cseg];
        short8* dstp = (short8*)&Bb[(size_t)(r0 + row) * 128 + cseg];
#pragma unroll
        for (int u = 0; u < 4; u++) dstp[u] = srcp[u];
    }
}

// ---------------- GAT aggregation: TWO nodes per wave, 32 lanes each ----------------
// Lane handles 4 channels (one uint2 = 2 dwords of bf16x2). One wave round
// completes 2 edges -> ~9 VALU insts/edge vs ~12 for one-node-per-wave.
// Alphas pre-scaled by 1/s before the loop. head = hl>>4 (uniform per lane).
__global__ void k_gat_agg(const uint2* __restrict__ Bu2, const float4* __restrict__ asadv,
                          const int* __restrict__ offs, const int* __restrict__ counts,
                          const int* __restrict__ adj, const float* __restrict__ biasF,
                          uint2* __restrict__ Au2, float2* __restrict__ pE,
                          int n, int dorelu) {
    int wave = (blockIdx.x * blockDim.x + threadIdx.x) >> 6;
    int lane = threadIdx.x & 63;
    int hl = lane & 31;          // lane within node-half
    int hb = lane & 32;          // shfl broadcast base for this half
    int node = wave * 2 + (lane >> 5);
    if (node >= n) return;
    int head = hl >> 4;          // channels 4hl..4hl+3

    float4 self = asadv[node];
    float ad0 = self.z, ad1 = self.w;
    float es0 = __expf(leaky(self.x + ad0));
    float es1 = __expf(leaky(self.y + ad1));

    int o = offs[node], c = counts[node];
    uint2 hvs = Bu2[(size_t)node * 32 + hl];
    float acc0, acc1, acc2, acc3;

    if (c <= 32) {
        // ---- fast path: alphas in registers (one neighbor per lane of the half) ----
        int src_r = 0;
        float p0 = 0.f, p1 = 0.f;
        if (hl < c) {
            src_r = adj[o + hl];
            float4 av = asadv[src_r];
            p0 = __expf(leaky(av.x + ad0));
            p1 = __expf(leaky(av.y + ad1));
        }
        float t0 = p0, t1 = p1;
#pragma unroll
        for (int mask = 1; mask <= 16; mask <<= 1) {
            t0 += __shfl_xor(t0, mask);
            t1 += __shfl_xor(t1, mask);
        }
        float inv0 = 1.f / (es0 + t0 + 1e-16f);
        float inv1 = 1.f / (es1 + t1 + 1e-16f);
        p0 *= inv0;                       // pre-scaled alphas
        p1 *= inv1;
        float aself = head ? es1 * inv1 : es0 * inv0;
        acc0 = aself * lo2f(hvs.x);
        acc1 = aself * hi2f(hvs.x);
        acc2 = aself * lo2f(hvs.y);
        acc3 = aself * hi2f(hvs.y);

        int sc = __shfl(src_r, hb);
        uint2 hv = make_uint2(0u, 0u);
        if (c > 0) hv = Bu2[(size_t)sc * 32 + hl];
        for (int i = 0; i < c; i++) {
            uint2 hvc = hv;
            float a0 = __shfl(p0, hb + i);
            float a1 = __shfl(p1, hb + i);
            int nx = (i + 1 < c) ? i + 1 : i;
            int s2 = __shfl(src_r, hb + nx);
            if (i + 1 < c) hv = Bu2[(size_t)s2 * 32 + hl];
            float a = head ? a1 : a0;
            acc0 += a * lo2f(hvc.x);
            acc1 += a * hi2f(hvc.x);
            acc2 += a * lo2f(hvc.y);
            acc3 += a * hi2f(hvc.y);
        }
    } else {
        // ---- slow path (rare, c>32): alphas staged in global scratch ----
        float sum0 = es0, sum1 = es1;
        for (int base = 0; base < c; base += 32) {
            int i = base + hl;
            float p0 = 0.f, p1 = 0.f;
            if (i < c) {
                int s = adj[o + i];
                float4 av = asadv[s];
                p0 = __expf(leaky(av.x + ad0));
                p1 = __expf(leaky(av.y + ad1));
                pE[o + i] = make_float2(p0, p1);
            }
            float t0 = p0, t1 = p1;
#pragma unroll
            for (int mask = 1; mask <= 16; mask <<= 1) {
                t0 += __shfl_xor(t0, mask);
                t1 += __shfl_xor(t1, mask);
            }
            sum0 += t0; sum1 += t1;
        }
        float inv0 = 1.f / (sum0 + 1e-16f);
        float inv1 = 1.f / (sum1 + 1e-16f);
        float aself = head ? es1 * inv1 : es0 * inv0;
        float invh = head ? inv1 : inv0;
        acc0 = aself * lo2f(hvs.x);
        acc1 = aself * hi2f(hvs.x);
        acc2 = aself * lo2f(hvs.y);
        acc3 = aself * hi2f(hvs.y);
        for (int i = 0; i < c; i++) {
            int s = adj[o + i];
            float2 pp = pE[o + i];
            uint2 hv = Bu2[(size_t)s * 32 + hl];
            float a = (head ? pp.y : pp.x) * invh;
            acc0 += a * lo2f(hv.x);
            acc1 += a * hi2f(hv.x);
            acc2 += a * lo2f(hv.y);
            acc3 += a * hi2f(hv.y);
        }
    }

    float4 bb = ((const float4*)biasF)[hl];
    float o0 = acc0 + bb.x;
    float o1 = acc1 + bb.y;
    float o2 = acc2 + bb.z;
    float o3 = acc3 + bb.w;
    if (dorelu) {
        o0 = fmaxf(o0, 0.f); o1 = fmaxf(o1, 0.f);
        o2 = fmaxf(o2, 0.f); o3 = fmaxf(o3, 0.f);
    }
    Au2[(size_t)node * 32 + hl] =
        make_uint2(((unsigned)f2us(o1) << 16) | f2us(o0),
                   ((unsigned)f2us(o3) << 16) | f2us(o2));
}

// ---------------- heads: one block (4 waves) per graph ----------------
__global__ __launch_bounds__(256) void k_heads(
    const unsigned short* __restrict__ Ab, const void* __restrict__ x,
    const int* __restrict__ node0,
    const void* sW, const void* sb,
    const void* pW1, const void* pb1, const void* pW2, const void* pb2,
    const void* cW1, const void* cb1, const void* cW2, const void* cb2,
    const void* fW1, const void* fb1, const void* fW2, const void* fb2,
    const void* bW1, const void* bb1, const void* bW2, const void* bb2,
    const void* zW1, const void* zb1, const void* zW2, const void* zb2,
    void* __restrict__ outv, const int* __restrict__ flag) {
    int g = blockIdx.x;
    int t = threadIdx.x;
    int w = t >> 6;
    int lane = t & 63;
    int f32 = *flag;
    bf16* outb = (bf16*)outv;
    float* outf = (float*)outv;
    __shared__ float in150[152];
    __shared__ float part[4][64];
    __shared__ float zf[64];
    __shared__ float tmp[64];
    __shared__ float bin[96];

#define STORE_OUT(idx, val) do { if (f32) outf[idx] = (val); else outb[idx] = __float2bfloat16(val); } while (0)

    int n0 = node0[g];
    if (t < 128) in150[t] = us2f(Ab[(size_t)n0 * 128 + t]);
    else if (t < 150) in150[t] = ldw(x, (size_t)n0 * 128 + (t - 128), f32);
    __syncthreads();
    if (t >= 64 && t < 86) bin[t] = in150[128 + (t - 64)];

    {
        int i0 = w * 38, i1 = min(150, i0 + 38);
        float p = 0.f;
        for (int i = i0; i < i1; i++) p += in150[i] * ldw(sW, (size_t)i * 64 + lane, f32);
        part[w][lane] = p;
    }
    __syncthreads();
    if (w == 0) {
        float a = part[0][lane] + part[1][lane] + part[2][lane] + part[3][lane]
                + ldw(sb, lane, f32);
        a = fmaxf(a, 0.f);
        zf[lane] = a;
        bin[lane] = a;
    }
    __syncthreads();

    for (int k = 0; k < 3; k++) {
        {
            int i0 = w * 16;
            float p = 0.f;
            for (int i = i0; i < i0 + 16; i++)
                p += zf[i] * ldw(pW1, (size_t)k * 4096 + (size_t)i * 64 + lane, f32);
            part[w][lane] = p;
        }
        __syncthreads();
        if (w == 0) {
            float a = part[0][lane] + part[1][lane] + part[2][lane] + part[3][lane]
                    + ldw(pb1, k * 64 + lane, f32);
            tmp[lane] = fmaxf(a, 0.f);
        }
        __syncthreads();
        if (w < 3) {
            float v = tmp[lane] * ldw(pW2, (size_t)k * 192 + (size_t)lane * 3 + w, f32);
#pragma unroll
            for (int mask = 1; mask <= 32; mask <<= 1) v += __shfl_xor(v, mask);
            if (lane == 0) STORE_OUT(k * 768 + g * 3 + w, v + ldw(pb2, k * 3 + w, f32));
        }
        __syncthreads();
    }

    {
        int i0 = w * 16;
        float p = 0.f;
        for (int i = i0; i < i0 + 16; i++)
            p += zf[i] * ldw(cW1, (size_t)i * 64 + lane, f32);
        part[w][lane] = p;
    }
    __syncthreads();
    if (w == 0) {
        float a = part[0][lane] + part[1][lane] + part[2][lane] + part[3][lane]
                + ldw(cb1, lane, f32);
        tmp[lane] = fmaxf(a, 0.f);
    }
    __syncthreads();
    for (int base = 0; base < 5; base += 4) {
        int o = base + w;
        if (o < 5) {
            float v = tmp[lane] * ldw(cW2, (size_t)lane * 5 + o, f32);
#pragma unroll
            for (int mask = 1; mask <= 32; mask <<= 1) v += __shfl_xor(v, mask);
            if (lane == 0) {
                float r = v + ldw(cb2, o, f32);
                bin[86 + o] = r;
                STORE_OUT(2304 + g * 5 + o, r);
            }
        }
        __syncthreads();
    }

    for (int k = 0; k < 2; k++) {
        {
            int i0 = w * 16;
            float p = 0.f;
            for (int i = i0; i < i0 + 16; i++)
                p += zf[i] * ldw(fW1, (size_t)k * 4096 + (size_t)i * 64 + lane, f32);
            part[w][lane] = p;
        }
        __syncthreads();
        if (w == 0) {
            float a = part[0][lane] + part[1][lane] + part[2][lane] + part[3][lane]
                    + ldw(fb1, k * 64 + lane, f32);
            tmp[lane] = fmaxf(a, 0.f);
        }
        __syncthreads();
        if (w == 0) {
            float v = tmp[lane] * ldw(fW2, k * 64 + lane, f32);
#pragma unroll
            for (int mask = 1; mask <= 32; mask <<= 1) v += __shfl_xor(v, mask);
            if (lane == 0) {
                float r = v + ldw(fb2, k, f32);
                bin[91 + k] = r;
                STORE_OUT(3584 + k * 256 + g, r);
            }
        }
        __syncthreads();
    }

    {
        int i0 = w * 24, i1 = min(93, i0 + 24);
        float p = 0.f;
        for (int i = i0; i < i1; i++) p += bin[i] * ldw(bW1, (size_t)i * 64 + lane, f32);
        part[w][lane] = p;
    }
    __syncthreads();
    if (w == 0) {
        float a = part[0][lane] + part[1][lane] + part[2][lane] + part[3][lane]
                + ldw(bb1, lane, f32);
        tmp[lane] = fmaxf(a, 0.f);
    }
    __syncthreads();
    if (w == 0) {
        float v = tmp[lane] * ldw(bW2, lane, f32);
#pragma unroll
        for (int mask = 1; mask <= 32; mask <<= 1) v += __shfl_xor(v, mask);
        if (lane == 0) {
            float r = v + ldw(bb2, 0, f32);
            bin[93] = r;
            STORE_OUT(4096 + g, r);
        }
    }
    __syncthreads();

    {
        int i0 = w * 24, i1 = min(94, i0 + 24);
        float p = 0.f;
        for (int i = i0; i < i1; i++) p += bin[i] * ldw(zW1, (size_t)i * 64 + lane, f32);
        part[w][lane] = p;
    }
    __syncthreads();
    if (w == 0) {
        float a = part[0][lane] + part[1][lane] + part[2][lane] + part[3][lane]
                + ldw(zb1, lane, f32);
        tmp[lane] = fmaxf(a, 0.f);
    }
    __syncthreads();
    for (int base = 0; base < 8; base += 4) {
        int o = base + w;
        float v = tmp[lane] * ldw(zW2, (size_t)lane * 8 + o, f32);
#pragma unroll
        for (int mask = 1; mask <= 32; mask <<= 1) v += __shfl_xor(v, mask);
        if (lane == 0) STORE_OUT(4352 + g * 8 + o, v + ldw(zb2, o, f32));
    }
#undef STORE_OUT
}

// ---------------- host ----------------

extern "C" void kernel_launch(void* const* d_in, const int* in_sizes, int n_in,
                              void* d_out, int out_size, void* d_ws, size_t ws_size,
                              hipStream_t stream) {
    const void* x     = d_in[0];
    const int*  ei    = (const int*)d_in[1];
    const int*  batch = (const int*)d_in[2];

    int N = in_sizes[0] / 128;
    int E = in_sizes[1] / 2;

    char* w = (char*)d_ws;
    float4* asad = (float4*)w;              w += (size_t)N * 16;
    unsigned short* A = (unsigned short*)w; w += (size_t)N * 128 * 2;
    unsigned short* B = (unsigned short*)w; w += (size_t)N * 128 * 2;
    float2* pE = (float2*)w;                w += (size_t)E * 8;
    unsigned short* Wt = (unsigned short*)w; w += 3 * 16384 * 2;
    float* asF = (float*)w;                 w += 384 * 4;
    float* adF = (float*)w;                 w += 384 * 4;
    float* bF = (float*)w;                  w += 384 * 4;
    int* counts = (int*)w;                  w += (size_t)N * 4;
    int* offs = (int*)w;                    w += (size_t)N * 4;
    int* cursor = (int*)w;                  w += (size_t)N * 4;
    int* adj = (int*)w;                     w += (size_t)E * 4;
    int* bsums = (int*)w;                   w += 512 * 4;
    int* node0 = (int*)w;                   w += 256 * 4;
    int* flag = (int*)w;                    w += 64;

    int nb = (N + 255) / 256;

    k_zero<<<1, 64, 0, stream>>>(flag, 1);
    k_detect<<<16, 256, 0, stream>>>(x, flag);

    k_prep_x<<<(N * 128 + 255) / 256, 256, 0, stream>>>(x, A, N * 128, flag);
    k_prep_w<<<192, 256, 0, stream>>>(d_in[3], Wt, flag);
    k_prep_small<<<2, 256, 0, stream>>>(d_in[4], d_in[5], d_in[6], asF, adF, bF, flag);

    k_zero<<<nb, 256, 0, stream>>>(counts, N);
    k_hist<<<(E + 255) / 256, 256, 0, stream>>>(ei, counts, E);
    k_scan1<<<nb, 256, 0, stream>>>(counts, offs, bsums, N);
    k_scan2<<<1, 512, 0, stream>>>(bsums, nb);
    k_scan3<<<nb, 256, 0, stream>>>(offs, cursor, bsums, N);
    k_scatter<<<(E + 255) / 256, 256, 0, stream>>>(ei, cursor, adj, E);
    k_node0<<<nb, 256, 0, stream>>>(batch, node0, N);

    // agg grid: 2 nodes per wave, 4 waves per block
    int nwaves = (N + 1) / 2;
    int aggblocks = (nwaves + 3) / 4;
    for (int l = 0; l < 3; l++) {
        k_gemm_mfma<<<(N + 63) / 64, 256, 0, stream>>>(
            A, Wt + (size_t)l * 16384, B, asad, asF + l * 128, adF + l * 128, N);
        k_gat_agg<<<aggblocks, 256, 0, stream>>>(
            (const uint2*)B, asad, offs, counts, adj,
            bF + l * 128, (uint2*)A, pE, N, (l < 2) ? 1 : 0);
    }

    k_heads<<<256, 256, 0, stream>>>(A, x, node0,
                                     d_in[7], d_in[8], d_in[9], d_in[10], d_in[11], d_in[12],
                                     d_in[13], d_in[14], d_in[15], d_in[16],
                                     d_in[17], d_in[18], d_in[19], d_in[20],
                                     d_in[21], d_in[22], d_in[23], d_in[24],
                                     d_in[25], d_in[26], d_in[27], d_in[28],
                                     d_out, flag);
}

// Round 7
// 603.295 us; speedup vs baseline: 1.9249x; 1.1415x over previous
//
#include <hip/hip_runtime.h>
#include <hip/hip_bf16.h>

typedef __hip_bfloat16 bf16;
typedef __attribute__((ext_vector_type(8))) short short8;
typedef __attribute__((ext_vector_type(4))) float floatx4;

__device__ __forceinline__ float b2f(bf16 v) { return __bfloat162float(v); }
__device__ __forceinline__ float us2f(unsigned short u) {
    return __uint_as_float(((unsigned)u) << 16);
}
__device__ __forceinline__ unsigned short f2us(float f) {
    bf16 h = __float2bfloat16(f);
    return *(unsigned short*)&h;
}
__device__ __forceinline__ float lo2f(unsigned hv) { return __uint_as_float(hv << 16); }
__device__ __forceinline__ float hi2f(unsigned hv) { return __uint_as_float(hv & 0xffff0000u); }
__device__ __forceinline__ float leaky(float v) { return v > 0.f ? v : 0.2f * v; }

// flag-aware raw-input read by ELEMENT index: flag==1 -> f32 storage, else bf16
__device__ __forceinline__ float ldw(const void* p, size_t i, int f32) {
    return f32 ? ((const float*)p)[i] : b2f(((const bf16*)p)[i]);
}

// ---------------- dtype detection ----------------
__global__ void k_detect(const void* x, int* flag) {
    int i = blockIdx.x * blockDim.x + threadIdx.x;
    float v = b2f(((const bf16*)x)[i]);
    if (!(fabsf(v) < 1e10f)) atomicOr(flag, 1);  // NaN/inf/huge -> f32 storage
}

__global__ void k_zero(int* __restrict__ p, int n) {
    int i = blockIdx.x * blockDim.x + threadIdx.x;
    if (i < n) p[i] = 0;
}

// ---------------- prep ----------------
__global__ void k_prep_x(const void* __restrict__ x, unsigned short* __restrict__ Ab,
                         int n, const int* __restrict__ flag) {
    int i = blockIdx.x * 256 + threadIdx.x;
    int f32 = *flag;
    if (i < n) Ab[i] = f2us(ldw(x, i, f32));
}

// Wt[l][n][k] (bf16) from gat_W[l][k][n]
__global__ void k_prep_w(const void* __restrict__ gw, unsigned short* __restrict__ Wt,
                         const int* __restrict__ flag) {
    int i = blockIdx.x * 256 + threadIdx.x;  // i < 3*16384
    int f32 = *flag;
    int l = i >> 14, rem = i & 16383, n = rem >> 7, k = rem & 127;
    Wt[i] = f2us(ldw(gw, (size_t)l * 16384 + (size_t)k * 128 + n, f32));
}

__global__ void k_prep_small(const void* as_, const void* ad_, const void* b_,
                             float* asF, float* adF, float* bF,
                             const int* __restrict__ flag) {
    int i = blockIdx.x * blockDim.x + threadIdx.x;
    int f32 = *flag;
    if (i < 384) {
        asF[i] = ldw(as_, i, f32);
        adF[i] = ldw(ad_, i, f32);
        bF[i] = ldw(b_, i, f32);
    }
}

// ---------------- graph build ----------------
// hist + rank capture: the atomic's return value is the edge's stable rank
// within its dst bucket (free — the atomic already pays the round-trip).
__global__ void k_hist(const int* __restrict__ ei, int* __restrict__ counts,
                       int* __restrict__ rank, int E) {
    int e = blockIdx.x * blockDim.x + threadIdx.x;
    if (e < E) rank[e] = atomicAdd(&counts[ei[E + e]], 1);
}

__global__ void k_scan1(const int* __restrict__ counts, int* __restrict__ offs,
                        int* __restrict__ bsums, int n) {
    __shared__ int s[256];
    int tid = threadIdx.x;
    int i = blockIdx.x * 256 + tid;
    int v = (i < n) ? counts[i] : 0;
    s[tid] = v;
    __syncthreads();
    for (int d = 1; d < 256; d <<= 1) {
        int t = (tid >= d) ? s[tid - d] : 0;
        __syncthreads();
        s[tid] += t;
        __syncthreads();
    }
    int incl = s[tid];
    if (i < n) offs[i] = incl - v;
    if (tid == 255) bsums[blockIdx.x] = incl;
}

__global__ void k_scan2(int* __restrict__ bsums, int nb) {
    __shared__ int s[512];
    int tid = threadIdx.x;
    int v = (tid < nb) ? bsums[tid] : 0;
    s[tid] = v;
    __syncthreads();
    for (int d = 1; d < 512; d <<= 1) {
        int t = (tid >= d) ? s[tid - d] : 0;
        __syncthreads();
        s[tid] += t;
        __syncthreads();
    }
    bsums[tid] = s[tid] - v;
}

__global__ void k_scan3(int* __restrict__ offs, const int* __restrict__ bsums, int n) {
    int i = blockIdx.x * 256 + threadIdx.x;
    if (i < n) offs[i] += bsums[blockIdx.x];
}

// atomic-free scatter: pos = offs[dst] + rank[e]; stores have no consumers,
// so they pile up in flight instead of serializing behind atomics.
__global__ void k_scatter(const int* __restrict__ ei, const int* __restrict__ offs,
                          const int* __restrict__ rank, int* __restrict__ adj, int E) {
    int e = blockIdx.x * blockDim.x + threadIdx.x;
    if (e < E) {
        int d = ei[E + e];
        adj[offs[d] + rank[e]] = ei[e];
    }
}

__global__ void k_node0(const int* __restrict__ batch, int* __restrict__ node0, int n) {
    int i = blockIdx.x * blockDim.x + threadIdx.x;
    if (i < n) {
        int b = batch[i];
        if (i == 0 || batch[i - 1] != b) node0[b] = i;
    }
}

// ---------------- MFMA GEMM + fused attention scalars ----------------
__global__ __launch_bounds__(256) void k_gemm_mfma(
    const unsigned short* __restrict__ Ab, const unsigned short* __restrict__ Wt,
    unsigned short* __restrict__ Bb, float4* __restrict__ asadv,
    const float* __restrict__ asF, const float* __restrict__ adF, int N) {
    __shared__ unsigned short As[64 * 136];  // staging + C-transpose buffer

    int t = threadIdx.x;
    int r0 = blockIdx.x * 64;

    const short8* Ag = (const short8*)(Ab + (size_t)r0 * 128);
    for (int ch = t; ch < 1024; ch += 256) {
        int row = ch >> 4, c8 = ch & 15;
        *(short8*)&As[row * 136 + c8 * 8] = Ag[ch];
    }
    __syncthreads();

    int lane = t & 63;
    int w = t >> 6;
    int ln = lane & 15;
    int quad = lane >> 4;

    short8 afrag[4];
#pragma unroll
    for (int kt = 0; kt < 4; kt++)
        afrag[kt] = *(const short8*)&As[(w * 16 + ln) * 136 + kt * 32 + quad * 8];
    __syncthreads();

    floatx4 acc[8];
#pragma unroll
    for (int nt = 0; nt < 8; nt++) acc[nt] = (floatx4){0.f, 0.f, 0.f, 0.f};

#pragma unroll
    for (int nt = 0; nt < 8; nt++) {
        const unsigned short* wp = Wt + (size_t)(nt * 16 + ln) * 128 + quad * 8;
#pragma unroll
        for (int kt = 0; kt < 4; kt++) {
            short8 bfrag = *(const short8*)(wp + kt * 32);
            acc[nt] = __builtin_amdgcn_mfma_f32_16x16x32_bf16(afrag[kt], bfrag, acc[nt], 0, 0, 0);
        }
    }

    float as0[4] = {0, 0, 0, 0}, as1[4] = {0, 0, 0, 0};
    float ad0[4] = {0, 0, 0, 0}, ad1[4] = {0, 0, 0, 0};
#pragma unroll
    for (int nt = 0; nt < 8; nt++) {
        float asc = asF[nt * 16 + ln];
        float adc = adF[nt * 16 + ln];
#pragma unroll
        for (int r = 0; r < 4; r++) {
            float v = acc[nt][r];
            As[(w * 16 + quad * 4 + r) * 136 + nt * 16 + ln] = f2us(v);
            if (nt < 4) { as0[r] += v * asc; ad0[r] += v * adc; }
            else        { as1[r] += v * asc; ad1[r] += v * adc; }
        }
    }
#pragma unroll
    for (int mask = 1; mask <= 8; mask <<= 1) {
#pragma unroll
        for (int r = 0; r < 4; r++) {
            as0[r] += __shfl_xor(as0[r], mask);
            as1[r] += __shfl_xor(as1[r], mask);
            ad0[r] += __shfl_xor(ad0[r], mask);
            ad1[r] += __shfl_xor(ad1[r], mask);
        }
    }
    if (ln == 0) {
#pragma unroll
        for (int r = 0; r < 4; r++) {
            int row = r0 + w * 16 + quad * 4 + r;
            asadv[row] = make_float4(as0[r], as1[r], ad0[r], ad1[r]);
        }
    }
    __syncthreads();

    {
        int row = t >> 2;
        int cseg = (t & 3) * 32;
        const short8* srcp = (const short8*)&As[row * 136 + cseg];
        short8* dstp = (short8*)&Bb[(size_t)(r0 + row) * 128 + cseg];
#pragma unroll
        for (int u = 0; u < 4; u++) dstp[u] = srcp[u];
    }
}

// ---------------- GAT aggregation: TWO nodes per wave, 32 lanes each ----------------
__global__ void k_gat_agg(const uint2* __restrict__ Bu2, const float4* __restrict__ asadv,
                          const int* __restrict__ offs, const int* __restrict__ counts,
                          const int* __restrict__ adj, const float* __restrict__ biasF,
                          uint2* __restrict__ Au2, float2* __restrict__ pE,
                          int n, int dorelu) {
    int wave = (blockIdx.x * blockDim.x + threadIdx.x) >> 6;
    int lane = threadIdx.x & 63;
    int hl = lane & 31;          // lane within node-half
    int hb = lane & 32;          // shfl broadcast base for this half
    int node = wave * 2 + (lane >> 5);
    if (node >= n) return;
    int head = hl >> 4;          // channels 4hl..4hl+3

    float4 self = asadv[node];
    float ad0 = self.z, ad1 = self.w;
    float es0 = __expf(leaky(self.x + ad0));
    float es1 = __expf(leaky(self.y + ad1));

    int o = offs[node], c = counts[node];
    uint2 hvs = Bu2[(size_t)node * 32 + hl];
    float acc0, acc1, acc2, acc3;

    if (c <= 32) {
        int src_r = 0;
        float p0 = 0.f, p1 = 0.f;
        if (hl < c) {
            src_r = adj[o + hl];
            float4 av = asadv[src_r];
            p0 = __expf(leaky(av.x + ad0));
            p1 = __expf(leaky(av.y + ad1));
        }
        float t0 = p0, t1 = p1;
#pragma unroll
        for (int mask = 1; mask <= 16; mask <<= 1) {
            t0 += __shfl_xor(t0, mask);
            t1 += __shfl_xor(t1, mask);
        }
        float inv0 = 1.f / (es0 + t0 + 1e-16f);
        float inv1 = 1.f / (es1 + t1 + 1e-16f);
        p0 *= inv0;                       // pre-scaled alphas
        p1 *= inv1;
        float aself = head ? es1 * inv1 : es0 * inv0;
        acc0 = aself * lo2f(hvs.x);
        acc1 = aself * hi2f(hvs.x);
        acc2 = aself * lo2f(hvs.y);
        acc3 = aself * hi2f(hvs.y);

        int sc = __shfl(src_r, hb);
        uint2 hv = make_uint2(0u, 0u);
        if (c > 0) hv = Bu2[(size_t)sc * 32 + hl];
        for (int i = 0; i < c; i++) {
            uint2 hvc = hv;
            float a0 = __shfl(p0, hb + i);
            float a1 = __shfl(p1, hb + i);
            int nx = (i + 1 < c) ? i + 1 : i;
            int s2 = __shfl(src_r, hb + nx);
            if (i + 1 < c) hv = Bu2[(size_t)s2 * 32 + hl];
            float a = head ? a1 : a0;
            acc0 += a * lo2f(hvc.x);
            acc1 += a * hi2f(hvc.x);
            acc2 += a * lo2f(hvc.y);
            acc3 += a * hi2f(hvc.y);
        }
    } else {
        float sum0 = es0, sum1 = es1;
        for (int base = 0; base < c; base += 32) {
            int i = base + hl;
            float p0 = 0.f, p1 = 0.f;
            if (i < c) {
                int s = adj[o + i];
                float4 av = asadv[s];
                p0 = __expf(leaky(av.x + ad0));
                p1 = __expf(leaky(av.y + ad1));
                pE[o + i] = make_float2(p0, p1);
            }
            float t0 = p0, t1 = p1;
#pragma unroll
            for (int mask = 1; mask <= 16; mask <<= 1) {
                t0 += __shfl_xor(t0, mask);
                t1 += __shfl_xor(t1, mask);
            }
            sum0 += t0; sum1 += t1;
        }
        float inv0 = 1.f / (sum0 + 1e-16f);
        float inv1 = 1.f / (sum1 + 1e-16f);
        float aself = head ? es1 * inv1 : es0 * inv0;
        float invh = head ? inv1 : inv0;
        acc0 = aself * lo2f(hvs.x);
        acc1 = aself * hi2f(hvs.x);
        acc2 = aself * lo2f(hvs.y);
        acc3 = aself * hi2f(hvs.y);
        for (int i = 0; i < c; i++) {
            int s = adj[o + i];
            float2 pp = pE[o + i];
            uint2 hv = Bu2[(size_t)s * 32 + hl];
            float a = (head ? pp.y : pp.x) * invh;
            acc0 += a * lo2f(hv.x);
            acc1 += a * hi2f(hv.x);
            acc2 += a * lo2f(hv.y);
            acc3 += a * hi2f(hv.y);
        }
    }

    float4 bb = ((const float4*)biasF)[hl];
    float o0 = acc0 + bb.x;
    float o1 = acc1 + bb.y;
    float o2 = acc2 + bb.z;
    float o3 = acc3 + bb.w;
    if (dorelu) {
        o0 = fmaxf(o0, 0.f); o1 = fmaxf(o1, 0.f);
        o2 = fmaxf(o2, 0.f); o3 = fmaxf(o3, 0.f);
    }
    Au2[(size_t)node * 32 + hl] =
        make_uint2(((unsigned)f2us(o1) << 16) | f2us(o0),
                   ((unsigned)f2us(o3) << 16) | f2us(o2));
}

// ---------------- heads: one block (4 waves) per graph ----------------
__global__ __launch_bounds__(256) void k_heads(
    const unsigned short* __restrict__ Ab, const void* __restrict__ x,
    const int* __restrict__ node0,
    const void* sW, const void* sb,
    const void* pW1, const void* pb1, const void* pW2, const void* pb2,
    const void* cW1, const void* cb1, const void* cW2, const void* cb2,
    const void* fW1, const void* fb1, const void* fW2, const void* fb2,
    const void* bW1, const void* bb1, const void* bW2, const void* bb2,
    const void* zW1, const void* zb1, const void* zW2, const void* zb2,
    void* __restrict__ outv, const int* __restrict__ flag) {
    int g = blockIdx.x;
    int t = threadIdx.x;
    int w = t >> 6;
    int lane = t & 63;
    int f32 = *flag;
    bf16* outb = (bf16*)outv;
    float* outf = (float*)outv;
    __shared__ float in150[152];
    __shared__ float part[4][64];
    __shared__ float zf[64];
    __shared__ float tmp[64];
    __shared__ float bin[96];

#define STORE_OUT(idx, val) do { if (f32) outf[idx] = (val); else outb[idx] = __float2bfloat16(val); } while (0)

    int n0 = node0[g];
    if (t < 128) in150[t] = us2f(Ab[(size_t)n0 * 128 + t]);
    else if (t < 150) in150[t] = ldw(x, (size_t)n0 * 128 + (t - 128), f32);
    __syncthreads();
    if (t >= 64 && t < 86) bin[t] = in150[128 + (t - 64)];

    {
        int i0 = w * 38, i1 = min(150, i0 + 38);
        float p = 0.f;
        for (int i = i0; i < i1; i++) p += in150[i] * ldw(sW, (size_t)i * 64 + lane, f32);
        part[w][lane] = p;
    }
    __syncthreads();
    if (w == 0) {
        float a = part[0][lane] + part[1][lane] + part[2][lane] + part[3][lane]
                + ldw(sb, lane, f32);
        a = fmaxf(a, 0.f);
        zf[lane] = a;
        bin[lane] = a;
    }
    __syncthreads();

    for (int k = 0; k < 3; k++) {
        {
            int i0 = w * 16;
            float p = 0.f;
            for (int i = i0; i < i0 + 16; i++)
                p += zf[i] * ldw(pW1, (size_t)k * 4096 + (size_t)i * 64 + lane, f32);
            part[w][lane] = p;
        }
        __syncthreads();
        if (w == 0) {
            float a = part[0][lane] + part[1][lane] + part[2][lane] + part[3][lane]
                    + ldw(pb1, k * 64 + lane, f32);
            tmp[lane] = fmaxf(a, 0.f);
        }
        __syncthreads();
        if (w < 3) {
            float v = tmp[lane] * ldw(pW2, (size_t)k * 192 + (size_t)lane * 3 + w, f32);
#pragma unroll
            for (int mask = 1; mask <= 32; mask <<= 1) v += __shfl_xor(v, mask);
            if (lane == 0) STORE_OUT(k * 768 + g * 3 + w, v + ldw(pb2, k * 3 + w, f32));
        }
        __syncthreads();
    }

    {
        int i0 = w * 16;
        float p = 0.f;
        for (int i = i0; i < i0 + 16; i++)
            p += zf[i] * ldw(cW1, (size_t)i * 64 + lane, f32);
        part[w][lane] = p;
    }
    __syncthreads();
    if (w == 0) {
        float a = part[0][lane] + part[1][lane] + part[2][lane] + part[3][lane]
                + ldw(cb1, lane, f32);
        tmp[lane] = fmaxf(a, 0.f);
    }
    __syncthreads();
    for (int base = 0; base < 5; base += 4) {
        int o = base + w;
        if (o < 5) {
            float v = tmp[lane] * ldw(cW2, (size_t)lane * 5 + o, f32);
#pragma unroll
            for (int mask = 1; mask <= 32; mask <<= 1) v += __shfl_xor(v, mask);
            if (lane == 0) {
                float r = v + ldw(cb2, o, f32);
                bin[86 + o] = r;
                STORE_OUT(2304 + g * 5 + o, r);
            }
        }
        __syncthreads();
    }

    for (int k = 0; k < 2; k++) {
        {
            int i0 = w * 16;
            float p = 0.f;
            for (int i = i0; i < i0 + 16; i++)
                p += zf[i] * ldw(fW1, (size_t)k * 4096 + (size_t)i * 64 + lane, f32);
            part[w][lane] = p;
        }
        __syncthreads();
        if (w == 0) {
            float a = part[0][lane] + part[1][lane] + part[2][lane] + part[3][lane]
                    + ldw(fb1, k * 64 + lane, f32);
            tmp[lane] = fmaxf(a, 0.f);
        }
        __syncthreads();
        if (w == 0) {
            float v = tmp[lane] * ldw(fW2, k * 64 + lane, f32);
#pragma unroll
            for (int mask = 1; mask <= 32; mask <<= 1) v += __shfl_xor(v, mask);
            if (lane == 0) {
                float r = v + ldw(fb2, k, f32);
                bin[91 + k] = r;
                STORE_OUT(3584 + k * 256 + g, r);
            }
        }
        __syncthreads();
    }

    {
        int i0 = w * 24, i1 = min(93, i0 + 24);
        float p = 0.f;
        for (int i = i0; i < i1; i++) p += bin[i] * ldw(bW1, (size_t)i * 64 + lane, f32);
        part[w][lane] = p;
    }
    __syncthreads();
    if (w == 0) {
        float a = part[0][lane] + part[1][lane] + part[2][lane] + part[3][lane]
                + ldw(bb1, lane, f32);
        tmp[lane] = fmaxf(a, 0.f);
    }
    __syncthreads();
    if (w == 0) {
        float v = tmp[lane] * ldw(bW2, lane, f32);
#pragma unroll
        for (int mask = 1; mask <= 32; mask <<= 1) v += __shfl_xor(v, mask);
        if (lane == 0) {
            float r = v + ldw(bb2, 0, f32);
            bin[93] = r;
            STORE_OUT(4096 + g, r);
        }
    }
    __syncthreads();

    {
        int i0 = w * 24, i1 = min(94, i0 + 24);
        float p = 0.f;
        for (int i = i0; i < i1; i++) p += bin[i] * ldw(zW1, (size_t)i * 64 + lane, f32);
        part[w][lane] = p;
    }
    __syncthreads();
    if (w == 0) {
        float a = part[0][lane] + part[1][lane] + part[2][lane] + part[3][lane]
                + ldw(zb1, lane, f32);
        tmp[lane] = fmaxf(a, 0.f);
    }
    __syncthreads();
    for (int base = 0; base < 8; base += 4) {
        int o = base + w;
        float v = tmp[lane] * ldw(zW2, (size_t)lane * 8 + o, f32);
#pragma unroll
        for (int mask = 1; mask <= 32; mask <<= 1) v += __shfl_xor(v, mask);
        if (lane == 0) STORE_OUT(4352 + g * 8 + o, v + ldw(zb2, o, f32));
    }
#undef STORE_OUT
}

// ---------------- host ----------------

extern "C" void kernel_launch(void* const* d_in, const int* in_sizes, int n_in,
                              void* d_out, int out_size, void* d_ws, size_t ws_size,
                              hipStream_t stream) {
    const void* x     = d_in[0];
    const int*  ei    = (const int*)d_in[1];
    const int*  batch = (const int*)d_in[2];

    int N = in_sizes[0] / 128;
    int E = in_sizes[1] / 2;

    char* w = (char*)d_ws;
    float4* asad = (float4*)w;              w += (size_t)N * 16;
    unsigned short* A = (unsigned short*)w; w += (size_t)N * 128 * 2;
    unsigned short* B = (unsigned short*)w; w += (size_t)N * 128 * 2;
    float2* pE = (float2*)w;                w += (size_t)E * 8;
    unsigned short* Wt = (unsigned short*)w; w += 3 * 16384 * 2;
    float* asF = (float*)w;                 w += 384 * 4;
    float* adF = (float*)w;                 w += 384 * 4;
    float* bF = (float*)w;                  w += 384 * 4;
    int* counts = (int*)w;                  w += (size_t)N * 4;
    int* offs = (int*)w;                    w += (size_t)N * 4;
    int* rank = (int*)w;                    w += (size_t)E * 4;
    int* adj = (int*)w;                     w += (size_t)E * 4;
    int* bsums = (int*)w;                   w += 512 * 4;
    int* node0 = (int*)w;                   w += 256 * 4;
    int* flag = (int*)w;                    w += 64;

    int nb = (N + 255) / 256;

    k_zero<<<1, 64, 0, stream>>>(flag, 1);
    k_detect<<<16, 256, 0, stream>>>(x, flag);

    k_prep_x<<<(N * 128 + 255) / 256, 256, 0, stream>>>(x, A, N * 128, flag);
    k_prep_w<<<192, 256, 0, stream>>>(d_in[3], Wt, flag);
    k_prep_small<<<2, 256, 0, stream>>>(d_in[4], d_in[5], d_in[6], asF, adF, bF, flag);

    k_zero<<<nb, 256, 0, stream>>>(counts, N);
    k_hist<<<(E + 255) / 256, 256, 0, stream>>>(ei, counts, rank, E);
    k_scan1<<<nb, 256, 0, stream>>>(counts, offs, bsums, N);
    k_scan2<<<1, 512, 0, stream>>>(bsums, nb);
    k_scan3<<<nb, 256, 0, stream>>>(offs, bsums, N);
    k_scatter<<<(E + 255) / 256, 256, 0, stream>>>(ei, offs, rank, adj, E);
    k_node0<<<nb, 256, 0, stream>>>(batch, node0, N);

    // agg grid: 2 nodes per wave, 4 waves per block
    int nwaves = (N + 1) / 2;
    int aggblocks = (nwaves + 3) / 4;
    for (int l = 0; l < 3; l++) {
        k_gemm_mfma<<<(N + 63) / 64, 256, 0, stream>>>(
            A, Wt + (size_t)l * 16384, B, asad, asF + l * 128, adF + l * 128, N);
        k_gat_agg<<<aggblocks, 256, 0, stream>>>(
            (const uint2*)B, asad, offs, counts, adj,
            bF + l * 128, (uint2*)A, pE, N, (l < 2) ? 1 : 0);
    }

    k_heads<<<256, 256, 0, stream>>>(A, x, node0,
                                     d_in[7], d_in[8], d_in[9], d_in[10], d_in[11], d_in[12],
                                     d_in[13], d_in[14], d_in[15], d_in[16],
                                     d_in[17], d_in[18], d_in[19], d_in[20],
                                     d_in[21], d_in[22], d_in[23], d_in[24],
                                     d_in[25], d_in[26], d_in[27], d_in[28],
                                     d_out, flag);
}

// Round 9
// 585.476 us; speedup vs baseline: 1.9835x; 1.0304x over previous
//
#include <hip/hip_runtime.h>
#include <hip/hip_bf16.h>

typedef __hip_bfloat16 bf16;
typedef __attribute__((ext_vector_type(8))) short short8;
typedef __attribute__((ext_vector_type(4))) float floatx4;

__device__ __forceinline__ float b2f(bf16 v) { return __bfloat162float(v); }
__device__ __forceinline__ float us2f(unsigned short u) {
    return __uint_as_float(((unsigned)u) << 16);
}
__device__ __forceinline__ unsigned short f2us(float f) {
    bf16 h = __float2bfloat16(f);
    return *(unsigned short*)&h;
}
__device__ __forceinline__ float lo2f(unsigned hv) { return __uint_as_float(hv << 16); }
__device__ __forceinline__ float hi2f(unsigned hv) { return __uint_as_float(hv & 0xffff0000u); }
__device__ __forceinline__ float leaky(float v) { return v > 0.f ? v : 0.2f * v; }

// flag-aware raw-input read by ELEMENT index: flag==1 -> f32 storage, else bf16
__device__ __forceinline__ float ldw(const void* p, size_t i, int f32) {
    return f32 ? ((const float*)p)[i] : b2f(((const bf16*)p)[i]);
}

// ---------------- dtype detection ----------------
__global__ void k_detect(const void* x, int* flag) {
    int i = blockIdx.x * blockDim.x + threadIdx.x;
    float v = b2f(((const bf16*)x)[i]);
    if (!(fabsf(v) < 1e10f)) atomicOr(flag, 1);  // NaN/inf/huge -> f32 storage
}

// ---------------- fused prep: x->bf16, W transpose->bf16, small weights, node0 ----
__global__ void k_prep_fused(const void* __restrict__ x, unsigned short* __restrict__ Ab,
                             int nx128,
                             const void* __restrict__ gw, unsigned short* __restrict__ Wt,
                             const void* as_, const void* ad_, const void* b_,
                             float* asF, float* adF, float* bF,
                             const int* __restrict__ batch, int* __restrict__ node0, int N,
                             const int* __restrict__ flag, int nbx, int nbN) {
    int b = blockIdx.x;
    int t = threadIdx.x;
    int f32 = *flag;
    if (b < nbx) {
        int i = b * 256 + t;
        if (i < nx128) Ab[i] = f2us(ldw(x, i, f32));
    } else if (b < nbx + 192) {
        int i = (b - nbx) * 256 + t;  // exactly 3*16384
        int l = i >> 14, rem = i & 16383, n = rem >> 7, k = rem & 127;
        Wt[i] = f2us(ldw(gw, (size_t)l * 16384 + (size_t)k * 128 + n, f32));
    } else if (b < nbx + 194) {
        int i = (b - nbx - 192) * 256 + t;
        if (i < 384) {
            asF[i] = ldw(as_, i, f32);
            adF[i] = ldw(ad_, i, f32);
            bF[i] = ldw(b_, i, f32);
        }
    } else {
        int i = (b - nbx - 194) * 256 + t;
        if (i < N) {
            int bb = batch[i];
            if (i == 0 || batch[i - 1] != bb) node0[bb] = i;
        }
    }
}

// ---------------- graph build ----------------
// hist + rank capture: the atomic's return value is the edge's stable rank
// within its dst bucket (free — the atomic already pays the round-trip).
__global__ void k_hist(const int* __restrict__ ei, int* __restrict__ counts,
                       int* __restrict__ rank, int E) {
    int e = blockIdx.x * blockDim.x + threadIdx.x;
    if (e < E) rank[e] = atomicAdd(&counts[ei[E + e]], 1);
}

__global__ void k_scan1(const int* __restrict__ counts, int* __restrict__ offs,
                        int* __restrict__ bsums, int n) {
    __shared__ int s[256];
    int tid = threadIdx.x;
    int i = blockIdx.x * 256 + tid;
    int v = (i < n) ? counts[i] : 0;
    s[tid] = v;
    __syncthreads();
    for (int d = 1; d < 256; d <<= 1) {
        int t = (tid >= d) ? s[tid - d] : 0;
        __syncthreads();
        s[tid] += t;
        __syncthreads();
    }
    int incl = s[tid];
    if (i < n) offs[i] = incl - v;
    if (tid == 255) bsums[blockIdx.x] = incl;
}

__global__ void k_scan2(int* __restrict__ bsums, int nb) {
    __shared__ int s[512];
    int tid = threadIdx.x;
    int v = (tid < nb) ? bsums[tid] : 0;
    s[tid] = v;
    __syncthreads();
    for (int d = 1; d < 512; d <<= 1) {
        int t = (tid >= d) ? s[tid - d] : 0;
        __syncthreads();
        s[tid] += t;
        __syncthreads();
    }
    bsums[tid] = s[tid] - v;
}

__global__ void k_scan3(int* __restrict__ offs, const int* __restrict__ bsums, int n) {
    int i = blockIdx.x * 256 + threadIdx.x;
    if (i < n) offs[i] += bsums[blockIdx.x];
}

// atomic-free scatter
__global__ void k_scatter(const int* __restrict__ ei, const int* __restrict__ offs,
                          const int* __restrict__ rank, int* __restrict__ adj, int E) {
    int e = blockIdx.x * blockDim.x + threadIdx.x;
    if (e < E) {
        int d = ei[E + e];
        adj[offs[d] + rank[e]] = ei[e];
    }
}

// ---------------- MFMA GEMM + fused attention scalars ----------------
__global__ __launch_bounds__(256) void k_gemm_mfma(
    const unsigned short* __restrict__ Ab, const unsigned short* __restrict__ Wt,
    unsigned short* __restrict__ Bb, float4* __restrict__ asadv,
    const float* __restrict__ asF, const float* __restrict__ adF, int N) {
    __shared__ unsigned short As[64 * 136];  // staging + C-transpose buffer

    int t = threadIdx.x;
    int r0 = blockIdx.x * 64;

    const short8* Ag = (const short8*)(Ab + (size_t)r0 * 128);
    for (int ch = t; ch < 1024; ch += 256) {
        int row = ch >> 4, c8 = ch & 15;
        *(short8*)&As[row * 136 + c8 * 8] = Ag[ch];
    }
    __syncthreads();

    int lane = t & 63;
    int w = t >> 6;
    int ln = lane & 15;
    int quad = lane >> 4;

    short8 afrag[4];
#pragma unroll
    for (int kt = 0; kt < 4; kt++)
        afrag[kt] = *(const short8*)&As[(w * 16 + ln) * 136 + kt * 32 + quad * 8];
    __syncthreads();

    floatx4 acc[8];
#pragma unroll
    for (int nt = 0; nt < 8; nt++) acc[nt] = (floatx4){0.f, 0.f, 0.f, 0.f};

#pragma unroll
    for (int nt = 0; nt < 8; nt++) {
        const unsigned short* wp = Wt + (size_t)(nt * 16 + ln) * 128 + quad * 8;
#pragma unroll
        for (int kt = 0; kt < 4; kt++) {
            short8 bfrag = *(const short8*)(wp + kt * 32);
            acc[nt] = __builtin_amdgcn_mfma_f32_16x16x32_bf16(afrag[kt], bfrag, acc[nt], 0, 0, 0);
        }
    }

    float as0[4] = {0, 0, 0, 0}, as1[4] = {0, 0, 0, 0};
    float ad0[4] = {0, 0, 0, 0}, ad1[4] = {0, 0, 0, 0};
#pragma unroll
    for (int nt = 0; nt < 8; nt++) {
        float asc = asF[nt * 16 + ln];
        float adc = adF[nt * 16 + ln];
#pragma unroll
        for (int r = 0; r < 4; r++) {
            float v = acc[nt][r];
            As[(w * 16 + quad * 4 + r) * 136 + nt * 16 + ln] = f2us(v);
            if (nt < 4) { as0[r] += v * asc; ad0[r] += v * adc; }
            else        { as1[r] += v * asc; ad1[r] += v * adc; }
        }
    }
#pragma unroll
    for (int mask = 1; mask <= 8; mask <<= 1) {
#pragma unroll
        for (int r = 0; r < 4; r++) {
            as0[r] += __shfl_xor(as0[r], mask);
            as1[r] += __shfl_xor(as1[r], mask);
            ad0[r] += __shfl_xor(ad0[r], mask);
            ad1[r] += __shfl_xor(ad1[r], mask);
        }
    }
    if (ln == 0) {
#pragma unroll
        for (int r = 0; r < 4; r++) {
            int row = r0 + w * 16 + quad * 4 + r;
            asadv[row] = make_float4(as0[r], as1[r], ad0[r], ad1[r]);
        }
    }
    __syncthreads();

    {
        int row = t >> 2;
        int cseg = (t & 3) * 32;
        const short8* srcp = (const short8*)&As[row * 136 + cseg];
        short8* dstp = (short8*)&Bb[(size_t)(r0 + row) * 128 + cseg];
#pragma unroll
        for (int u = 0; u < 4; u++) dstp[u] = srcp[u];
    }
}

// ---------------- GAT aggregation: TWO nodes per wave, depth-4 pipeline ----------------
// Lane handles 4 channels (uint2). Fast path (c<=32): alphas in registers,
// 4 feature rows per node prefetched -> 8 edges/wave in flight (2 KB).
__global__ void k_gat_agg(const uint2* __restrict__ Bu2, const float4* __restrict__ asadv,
                          const int* __restrict__ offs, const int* __restrict__ counts,
                          const int* __restrict__ adj, const float* __restrict__ biasF,
                          uint2* __restrict__ Au2, float2* __restrict__ pE,
                          int n, int dorelu) {
    int wave = (blockIdx.x * blockDim.x + threadIdx.x) >> 6;
    int lane = threadIdx.x & 63;
    int hl = lane & 31;          // lane within node-half
    int hb = lane & 32;          // shfl broadcast base for this half
    int node = wave * 2 + (lane >> 5);
    if (node >= n) return;
    int head = hl >> 4;          // channels 4hl..4hl+3

    float4 self = asadv[node];
    float ad0 = self.z, ad1 = self.w;
    float es0 = __expf(leaky(self.x + ad0));
    float es1 = __expf(leaky(self.y + ad1));

    int o = offs[node], c = counts[node];
    uint2 hvs = Bu2[(size_t)node * 32 + hl];
    float acc0, acc1, acc2, acc3;

    if (c <= 32) {
        // ---- fast path ----
        int src_r = 0;
        float p0 = 0.f, p1 = 0.f;
        if (hl < c) {
            src_r = adj[o + hl];
            float4 av = asadv[src_r];
            p0 = __expf(leaky(av.x + ad0));
            p1 = __expf(leaky(av.y + ad1));
        }
        float t0 = p0, t1 = p1;
#pragma unroll
        for (int mask = 1; mask <= 16; mask <<= 1) {
            t0 += __shfl_xor(t0, mask);
            t1 += __shfl_xor(t1, mask);
        }
        float inv0 = 1.f / (es0 + t0 + 1e-16f);
        float inv1 = 1.f / (es1 + t1 + 1e-16f);
        p0 *= inv0;                       // pre-scaled alphas
        p1 *= inv1;
        float aself = head ? es1 * inv1 : es0 * inv0;
        acc0 = aself * lo2f(hvs.x);
        acc1 = aself * hi2f(hvs.x);
        acc2 = aself * lo2f(hvs.y);
        acc3 = aself * hi2f(hvs.y);

        // prologue: prefetch rows for edges 0..3
        uint2 hq[4];
#pragma unroll
        for (int j = 0; j < 4; j++) {
            int s2 = __shfl(src_r, hb + j);
            hq[j] = make_uint2(0u, 0u);
            if (j < c) hq[j] = Bu2[(size_t)s2 * 32 + hl];
        }

        for (int base = 0; base < c; base += 4) {
            uint2 cur[4];
            float av4[4];
#pragma unroll
            for (int j = 0; j < 4; j++) {
                cur[j] = hq[j];
                int idx = (base + j) & 31;
                float a0 = __shfl(p0, hb + idx);
                float a1 = __shfl(p1, hb + idx);
                float a = head ? a1 : a0;
                av4[j] = (base + j < c) ? a : 0.f;   // zero-guard tail (stale cur is finite)
            }
            // issue next 4 loads before consuming cur
#pragma unroll
            for (int j = 0; j < 4; j++) {
                int nx = base + 4 + j;
                int s2 = __shfl(src_r, hb + (nx & 31));
                if (nx < c) hq[j] = Bu2[(size_t)s2 * 32 + hl];
            }
#pragma unroll
            for (int j = 0; j < 4; j++) {
                acc0 += av4[j] * lo2f(cur[j].x);
                acc1 += av4[j] * hi2f(cur[j].x);
                acc2 += av4[j] * lo2f(cur[j].y);
                acc3 += av4[j] * hi2f(cur[j].y);
            }
        }
    } else {
        // ---- slow path (rare, c>32): alphas staged in global scratch ----
        float sum0 = es0, sum1 = es1;
        for (int base = 0; base < c; base += 32) {
            int i = base + hl;
            float p0 = 0.f, p1 = 0.f;
            if (i < c) {
                int s = adj[o + i];
                float4 av = asadv[s];
                p0 = __expf(leaky(av.x + ad0));
                p1 = __expf(leaky(av.y + ad1));
                pE[o + i] = make_float2(p0, p1);
            }
            float t0 = p0, t1 = p1;
#pragma unroll
            for (int mask = 1; mask <= 16; mask <<= 1) {
                t0 += __shfl_xor(t0, mask);
                t1 += __shfl_xor(t1, mask);
            }
            sum0 += t0; sum1 += t1;
        }
        float inv0 = 1.f / (sum0 + 1e-16f);
        float inv1 = 1.f / (sum1 + 1e-16f);
        float aself = head ? es1 * inv1 : es0 * inv0;
        float invh = head ? inv1 : inv0;
        acc0 = aself * lo2f(hvs.x);
        acc1 = aself * hi2f(hvs.x);
        acc2 = aself * lo2f(hvs.y);
        acc3 = aself * hi2f(hvs.y);
        for (int i = 0; i < c; i++) {
            int s = adj[o + i];
            float2 pp = pE[o + i];
            uint2 hv = Bu2[(size_t)s * 32 + hl];
            float a = (head ? pp.y : pp.x) * invh;
            acc0 += a * lo2f(hv.x);
            acc1 += a * hi2f(hv.x);
            acc2 += a * lo2f(hv.y);
            acc3 += a * hi2f(hv.y);
        }
    }

    float4 bb = ((const float4*)biasF)[hl];
    float o0 = acc0 + bb.x;
    float o1 = acc1 + bb.y;
    float o2 = acc2 + bb.z;
    float o3 = acc3 + bb.w;
    if (dorelu) {
        o0 = fmaxf(o0, 0.f); o1 = fmaxf(o1, 0.f);
        o2 = fmaxf(o2, 0.f); o3 = fmaxf(o3, 0.f);
    }
    Au2[(size_t)node * 32 + hl] =
        make_uint2(((unsigned)f2us(o1) << 16) | f2us(o0),
                   ((unsigned)f2us(o3) << 16) | f2us(o2));
}

// ---------------- heads: one block (4 waves) per graph ----------------
__global__ __launch_bounds__(256) void k_heads(
    const unsigned short* __restrict__ Ab, const void* __restrict__ x,
    const int* __restrict__ node0,
    const void* sW, const void* sb,
    const void* pW1, const void* pb1, const void* pW2, const void* pb2,
    const void* cW1, const void* cb1, const void* cW2, const void* cb2,
    const void* fW1, const void* fb1, const void* fW2, const void* fb2,
    const void* bW1, const void* bb1, const void* bW2, const void* bb2,
    const void* zW1, const void* zb1, const void* zW2, const void* zb2,
    void* __restrict__ outv, const int* __restrict__ flag) {
    int g = blockIdx.x;
    int t = threadIdx.x;
    int w = t >> 6;
    int lane = t & 63;
    int f32 = *flag;
    bf16* outb = (bf16*)outv;
    float* outf = (float*)outv;
    __shared__ float in150[152];
    __shared__ float part[4][64];
    __shared__ float zf[64];
    __shared__ float tmp[64];
    __shared__ float bin[96];

#define STORE_OUT(idx, val) do { if (f32) outf[idx] = (val); else outb[idx] = __float2bfloat16(val); } while (0)

    int n0 = node0[g];
    if (t < 128) in150[t] = us2f(Ab[(size_t)n0 * 128 + t]);
    else if (t < 150) in150[t] = ldw(x, (size_t)n0 * 128 + (t - 128), f32);
    __syncthreads();
    if (t >= 64 && t < 86) bin[t] = in150[128 + (t - 64)];

    {
        int i0 = w * 38, i1 = min(150, i0 + 38);
        float p = 0.f;
        for (int i = i0; i < i1; i++) p += in150[i] * ldw(sW, (size_t)i * 64 + lane, f32);
        part[w][lane] = p;
    }
    __syncthreads();
    if (w == 0) {
        float a = part[0][lane] + part[1][lane] + part[2][lane] + part[3][lane]
                + ldw(sb, lane, f32);
        a = fmaxf(a, 0.f);
        zf[lane] = a;
        bin[lane] = a;
    }
    __syncthreads();

    for (int k = 0; k < 3; k++) {
        {
            int i0 = w * 16;
            float p = 0.f;
            for (int i = i0; i < i0 + 16; i++)
                p += zf[i] * ldw(pW1, (size_t)k * 4096 + (size_t)i * 64 + lane, f32);
            part[w][lane] = p;
        }
        __syncthreads();
        if (w == 0) {
            float a = part[0][lane] + part[1][lane] + part[2][lane] + part[3][lane]
                    + ldw(pb1, k * 64 + lane, f32);
            tmp[lane] = fmaxf(a, 0.f);
        }
        __syncthreads();
        if (w < 3) {
            float v = tmp[lane] * ldw(pW2, (size_t)k * 192 + (size_t)lane * 3 + w, f32);
#pragma unroll
            for (int mask = 1; mask <= 32; mask <<= 1) v += __shfl_xor(v, mask);
            if (lane == 0) STORE_OUT(k * 768 + g * 3 + w, v + ldw(pb2, k * 3 + w, f32));
        }
        __syncthreads();
    }

    {
        int i0 = w * 16;
        float p = 0.f;
        for (int i = i0; i < i0 + 16; i++)
            p += zf[i] * ldw(cW1, (size_t)i * 64 + lane, f32);
        part[w][lane] = p;
    }
    __syncthreads();
    if (w == 0) {
        float a = part[0][lane] + part[1][lane] + part[2][lane] + part[3][lane]
                + ldw(cb1, lane, f32);
        tmp[lane] = fmaxf(a, 0.f);
    }
    __syncthreads();
    for (int base = 0; base < 5; base += 4) {
        int o = base + w;
        if (o < 5) {
            float v = tmp[lane] * ldw(cW2, (size_t)lane * 5 + o, f32);
#pragma unroll
            for (int mask = 1; mask <= 32; mask <<= 1) v += __shfl_xor(v, mask);
            if (lane == 0) {
                float r = v + ldw(cb2, o, f32);
                bin[86 + o] = r;
                STORE_OUT(2304 + g * 5 + o, r);
            }
        }
        __syncthreads();
    }

    for (int k = 0; k < 2; k++) {
        {
            int i0 = w * 16;
            float p = 0.f;
            for (int i = i0; i < i0 + 16; i++)
                p += zf[i] * ldw(fW1, (size_t)k * 4096 + (size_t)i * 64 + lane, f32);
            part[w][lane] = p;
        }
        __syncthreads();
        if (w == 0) {
            float a = part[0][lane] + part[1][lane] + part[2][lane] + part[3][lane]
                    + ldw(fb1, k * 64 + lane, f32);
            tmp[lane] = fmaxf(a, 0.f);
        }
        __syncthreads();
        if (w == 0) {
            float v = tmp[lane] * ldw(fW2, k * 64 + lane, f32);
#pragma unroll
            for (int mask = 1; mask <= 32; mask <<= 1) v += __shfl_xor(v, mask);
            if (lane == 0) {
                float r = v + ldw(fb2, k, f32);
                bin[91 + k] = r;
                STORE_OUT(3584 + k * 256 + g, r);
            }
        }
        __syncthreads();
    }

    {
        int i0 = w * 24, i1 = min(93, i0 + 24);
        float p = 0.f;
        for (int i = i0; i < i1; i++) p += bin[i] * ldw(bW1, (size_t)i * 64 + lane, f32);
        part[w][lane] = p;
    }
    __syncthreads();
    if (w == 0) {
        float a = part[0][lane] + part[1][lane] + part[2][lane] + part[3][lane]
                + ldw(bb1, lane, f32);
        tmp[lane] = fmaxf(a, 0.f);
    }
    __syncthreads();
    if (w == 0) {
        float v = tmp[lane] * ldw(bW2, lane, f32);
#pragma unroll
        for (int mask = 1; mask <= 32; mask <<= 1) v += __shfl_xor(v, mask);
        if (lane == 0) {
            float r = v + ldw(bb2, 0, f32);
            bin[93] = r;
            STORE_OUT(4096 + g, r);
        }
    }
    __syncthreads();

    {
        int i0 = w * 24, i1 = min(94, i0 + 24);
        float p = 0.f;
        for (int i = i0; i < i1; i++) p += bin[i] * ldw(zW1, (size_t)i * 64 + lane, f32);
        part[w][lane] = p;
    }
    __syncthreads();
    if (w == 0) {
        float a = part[0][lane] + part[1][lane] + part[2][lane] + part[3][lane]
                + ldw(zb1, lane, f32);
        tmp[lane] = fmaxf(a, 0.f);
    }
    __syncthreads();
    for (int base = 0; base < 8; base += 4) {
        int o = base + w;
        float v = tmp[lane] * ldw(zW2, (size_t)lane * 8 + o, f32);
#pragma unroll
        for (int mask = 1; mask <= 32; mask <<= 1) v += __shfl_xor(v, mask);
        if (lane == 0) STORE_OUT(4352 + g * 8 + o, v + ldw(zb2, o, f32));
    }
#undef STORE_OUT
}

// ---------------- host ----------------

extern "C" void kernel_launch(void* const* d_in, const int* in_sizes, int n_in,
                              void* d_out, int out_size, void* d_ws, size_t ws_size,
                              hipStream_t stream) {
    const void* x     = d_in[0];
    const int*  ei    = (const int*)d_in[1];
    const int*  batch = (const int*)d_in[2];

    int N = in_sizes[0] / 128;
    int E = in_sizes[1] / 2;

    char* w = (char*)d_ws;
    float4* asad = (float4*)w;              w += (size_t)N * 16;
    unsigned short* A = (unsigned short*)w; w += (size_t)N * 128 * 2;
    unsigned short* B = (unsigned short*)w; w += (size_t)N * 128 * 2;
    float2* pE = (float2*)w;                w += (size_t)E * 8;
    unsigned short* Wt = (unsigned short*)w; w += 3 * 16384 * 2;
    float* asF = (float*)w;                 w += 384 * 4;
    float* adF = (float*)w;                 w += 384 * 4;
    float* bF = (float*)w;                  w += 384 * 4;
    int* counts = (int*)w;                  w += (size_t)N * 4;
    int* offs = (int*)w;                    w += (size_t)N * 4;
    int* rank = (int*)w;                    w += (size_t)E * 4;
    int* adj = (int*)w;                     w += (size_t)E * 4;
    int* bsums = (int*)w;                   w += 512 * 4;
    int* node0 = (int*)w;                   w += 256 * 4;
    int* flag = (int*)w;                    w += 64;

    int nb = (N + 255) / 256;
    int nbx = (N * 128 + 255) / 256;

    hipMemsetAsync(flag, 0, 64, stream);
    hipMemsetAsync(counts, 0, (size_t)N * 4, stream);

    k_detect<<<16, 256, 0, stream>>>(x, flag);

    k_prep_fused<<<nbx + 194 + nb, 256, 0, stream>>>(
        x, A, N * 128, d_in[3], Wt, d_in[4], d_in[5], d_in[6],
        asF, adF, bF, batch, node0, N, flag, nbx, nb);

    k_hist<<<(E + 255) / 256, 256, 0, stream>>>(ei, counts, rank, E);
    k_scan1<<<nb, 256, 0, stream>>>(counts, offs, bsums, N);
    k_scan2<<<1, 512, 0, stream>>>(bsums, nb);
    k_scan3<<<nb, 256, 0, stream>>>(offs, bsums, N);
    k_scatter<<<(E + 255) / 256, 256, 0, stream>>>(ei, offs, rank, adj, E);

    // agg grid: 2 nodes per wave, 4 waves per block
    int nwaves = (N + 1) / 2;
    int aggblocks = (nwaves + 3) / 4;
    for (int l = 0; l < 3; l++) {
        k_gemm_mfma<<<(N + 63) / 64, 256, 0, stream>>>(
            A, Wt + (size_t)l * 16384, B, asad, asF + l * 128, adF + l * 128, N);
        k_gat_agg<<<aggblocks, 256, 0, stream>>>(
            (const uint2*)B, asad, offs, counts, adj,
            bF + l * 128, (uint2*)A, pE, N, (l < 2) ? 1 : 0);
    }

    k_heads<<<256, 256, 0, stream>>>(A, x, node0,
                                     d_in[7], d_in[8], d_in[9], d_in[10], d_in[11], d_in[12],
                                     d_in[13], d_in[14], d_in[15], d_in[16],
                                     d_in[17], d_in[18], d_in[19], d_in[20],
                                     d_in[21], d_in[22], d_in[23], d_in[24],
                                     d_in[25], d_in[26], d_in[27], d_in[28],
                                     d_out, flag);
}